// Round 25
// baseline (273.327 us; speedup 1.0000x reference)
//
#include <hip/hip_runtime.h>
#include <hip/hip_fp16.h>
#include <math.h>

#define N_NODES 20000
#define T_STEPS 8
#define E_EDGES 640000
#define TN (T_STEPS * N_NODES)   // 160000
#define TE (T_STEPS * E_EDGES)   // 5120000
#define HDIM 32
#define HEADS 2
#define NPB 8                    // nodes per block for lane-parallel node kernels
#define SCAN_BLOCKS 625          // TN / 256 exactly
#define GB 32                    // histogram blocks per timestep
#define CHUNK (E_EDGES / GB)     // 20000 edges per histogram block
#define NPAIR (N_NODES / 2)      // packed bins per timestep
#define GNT 2                    // GRU nodes per thread-group
#define GNB (8 * GNT)            // GRU nodes per block = 16 (1250 blocks exactly)

typedef _Float16 h2v __attribute__((ext_vector_type(2)));

__device__ __forceinline__ float lrelu02(float v) { return fmaxf(v, 0.2f * v); }
__device__ __forceinline__ float eluf(float v) { return v > 0.f ? v : expm1f(v); }
__device__ __forceinline__ float fsig(float v) {
    return __fdividef(1.f, 1.f + __expf(-v));
}
__device__ __forceinline__ float ftanh(float v) {
    return 1.f - __fdividef(2.f, __expf(2.f * v) + 1.f);
}

__device__ __forceinline__ float lane32_sum(float v) {
    v += __shfl_xor(v, 16);
    v += __shfl_xor(v, 8);
    v += __shfl_xor(v, 4);
    v += __shfl_xor(v, 2);
    v += __shfl_xor(v, 1);
    return v;
}

// dot of 4 halves x 4 halves accumulated into f32 (2x v_dot2_f32_f16)
__device__ __forceinline__ float dot4h(uint2 a, uint2 b, float c) {
    h2v a0 = *(h2v*)&a.x, a1 = *(h2v*)&a.y;
    h2v b0 = *(h2v*)&b.x, b1 = *(h2v*)&b.y;
    return __builtin_amdgcn_fdot2(a0, b0, __builtin_amdgcn_fdot2(a1, b1, c, false), false);
}

// load 8 fp16 channels (16 B, one dwordx4) -> two float4
__device__ __forceinline__ void ldh8(const __half* p, float4& f0, float4& f1) {
    uint4 u = *(const uint4*)p;
    __half2 a = *(__half2*)&u.x;
    __half2 b = *(__half2*)&u.y;
    __half2 c = *(__half2*)&u.z;
    __half2 d = *(__half2*)&u.w;
    float2 fa = __half22float2(a), fb = __half22float2(b);
    float2 fc = __half22float2(c), fd = __half22float2(d);
    f0 = make_float4(fa.x, fa.y, fb.x, fb.y);
    f1 = make_float4(fc.x, fc.y, fd.x, fd.y);
}

// ---- pass A: per-block LDS histogram + local scan + locally-sorted staging ----
__global__ void k_hist(const int* __restrict__ ei, unsigned char* __restrict__ hist8,
                       unsigned short* __restrict__ lrow16,
                       unsigned short* __restrict__ stagedG) {
    __shared__ int lh[NPAIR];                 // 40 KB: counts -> packed lrow
    __shared__ unsigned short sdst[CHUNK];    // 40 KB
    __shared__ unsigned short ssrc[CHUNK];    // 40 KB
    __shared__ int partial[1024];             // 4 KB
    int t = blockIdx.x & 7, b = blockIdx.x >> 3;
    for (int i = threadIdx.x; i < NPAIR; i += 1024) lh[i] = 0;
    __syncthreads();
    const int* srcp = ei + (size_t)t * 2 * E_EDGES + b * CHUNK;
    const int* dstp = srcp + E_EDGES;
    for (int j = threadIdx.x; j < CHUNK; j += 1024) {
        int dst = dstp[j];
        int src = srcp[j];
        sdst[j] = (unsigned short)dst;
        ssrc[j] = (unsigned short)src;
        atomicAdd(&lh[dst >> 1], (dst & 1) ? 65536 : 1);
    }
    __syncthreads();
    size_t bi = (size_t)t * GB + b;
    unsigned char* hp = hist8 + bi * N_NODES;
    for (int i = threadIdx.x; i < NPAIR; i += 1024) {
        int v = lh[i];
        uchar2 pk;
        pk.x = (unsigned char)(v & 0xff);
        pk.y = (unsigned char)((v >> 16) & 0xff);
        *(uchar2*)(hp + 2 * i) = pk;
    }
    __syncthreads();
    const int tpp = 10;   // 1024*10 >= NPAIR
    int i0 = threadIdx.x * tpp;
    int run = 0;
    for (int k = 0; k < tpp; ++k) {
        int i = i0 + k;
        if (i < NPAIR) {
            int v = lh[i];
            run += (v & 0xffff) + (v >> 16);
        }
    }
    partial[threadIdx.x] = run;
    __syncthreads();
    for (int off = 1; off < 1024; off <<= 1) {
        int add = (threadIdx.x >= off) ? partial[threadIdx.x - off] : 0;
        __syncthreads();
        partial[threadIdx.x] += add;
        __syncthreads();
    }
    int run2 = (threadIdx.x > 0) ? partial[threadIdx.x - 1] : 0;
    for (int k = 0; k < tpp; ++k) {
        int i = i0 + k;
        if (i < NPAIR) {
            int v = lh[i];
            int c0 = v & 0xffff, c1 = v >> 16;
            lh[i] = run2 | ((run2 + c0) << 16);   // packed (l0, l1)
            run2 += c0 + c1;
        }
    }
    __syncthreads();
    unsigned short* lp = lrow16 + bi * NPAIR;
    for (int i = threadIdx.x; i < NPAIR; i += 1024)
        lp[i] = (unsigned short)(lh[i] & 0xffff);
    __syncthreads();   // all lrow reads of lh done before atomics mutate lh
    unsigned short* stg = stagedG + bi * CHUNK;
    for (int j = threadIdx.x; j < CHUNK; j += 1024) {
        int dst = sdst[j];
        int old = atomicAdd(&lh[dst >> 1], (dst & 1) ? 65536 : 1);
        int pos = (old >> (16 * (dst & 1))) & 0xffff;
        stg[pos] = ssrc[j];
    }
}

// ---- pass B: per-(t,dst) prefix over blocks -> base (packed) + totals ----
__global__ void k_blkpre(const unsigned char* __restrict__ hist8, int* __restrict__ base,
                         int* __restrict__ cnt, const float* __restrict__ W1,
                         const float* __restrict__ as1, const float* __restrict__ ad1,
                         float* __restrict__ S4) {
    int i = blockIdx.x * blockDim.x + threadIdx.x;  // (t, pair)
    if (i == 0) {
        for (int hd = 0; hd < HEADS; ++hd) {
            float ss = 0.f, sd = 0.f;
            for (int c = 0; c < HDIM; ++c) {
                ss += W1[hd * HDIM + c] * as1[hd * HDIM + c];
                sd += W1[hd * HDIM + c] * ad1[hd * HDIM + c];
            }
            S4[hd] = ss;
            S4[HEADS + hd] = sd;
        }
    }
    if (i >= T_STEPS * NPAIR) return;
    int t = i / NPAIR, pr = i % NPAIR;
    int a0 = 0, a1 = 0;
    for (int b = 0; b < GB; ++b) {
        size_t bi = ((size_t)t * GB + b);
        uchar2 v = *(const uchar2*)(hist8 + bi * N_NODES + 2 * pr);
        base[bi * NPAIR + pr] = a0 | (a1 << 16);
        a0 += v.x;
        a1 += v.y;
    }
    cnt[t * N_NODES + 2 * pr] = a0;
    cnt[t * N_NODES + 2 * pr + 1] = a1;
}

// ---- scan (exclusive) over cnt[TN] -> row[TN+1] ----
__global__ void k_scan_a(const int* __restrict__ cnt, int* __restrict__ bsum) {
    __shared__ int s[256];
    int i = blockIdx.x * 256 + threadIdx.x;
    s[threadIdx.x] = (i < TN) ? cnt[i] : 0;
    __syncthreads();
    for (int off = 128; off > 0; off >>= 1) {
        if (threadIdx.x < off) s[threadIdx.x] += s[threadIdx.x + off];
        __syncthreads();
    }
    if (threadIdx.x == 0) bsum[blockIdx.x] = s[0];
}

__global__ void k_scan_b(const int* __restrict__ bsum, int* __restrict__ bpre) {
    __shared__ int s[256];
    __shared__ int carry;
    if (threadIdx.x == 0) carry = 0;
    __syncthreads();
    for (int base = 0; base < SCAN_BLOCKS; base += 256) {
        int i = base + threadIdx.x;
        int v = (i < SCAN_BLOCKS) ? bsum[i] : 0;
        s[threadIdx.x] = v;
        __syncthreads();
        for (int off = 1; off < 256; off <<= 1) {
            int add = (threadIdx.x >= off) ? s[threadIdx.x - off] : 0;
            __syncthreads();
            s[threadIdx.x] += add;
            __syncthreads();
        }
        if (i < SCAN_BLOCKS) bpre[i] = carry + s[threadIdx.x] - v;  // exclusive
        __syncthreads();
        if (threadIdx.x == 0) carry += s[255];
        __syncthreads();
    }
}

__global__ void k_scan_c(const int* __restrict__ cnt, const int* __restrict__ bpre,
                         int* __restrict__ row) {
    __shared__ int s[256];
    int i = blockIdx.x * 256 + threadIdx.x;
    int v = (i < TN) ? cnt[i] : 0;
    s[threadIdx.x] = v;
    __syncthreads();
    for (int off = 1; off < 256; off <<= 1) {
        int add = (threadIdx.x >= off) ? s[threadIdx.x - off] : 0;
        __syncthreads();
        s[threadIdx.x] += add;
        __syncthreads();
    }
    if (i < TN) row[i] = bpre[blockIdx.x] + s[threadIdx.x] - v;
    if (blockIdx.x == 0 && threadIdx.x == 0) row[TN] = TE;
}

// ---- pass C: per-bin copy from locally-sorted staging into global CSR ----
__global__ void k_scatter(const unsigned char* __restrict__ hist8,
                          const unsigned short* __restrict__ lrow16,
                          const int* __restrict__ row, const int* __restrict__ base,
                          const unsigned short* __restrict__ stagedG,
                          unsigned short* __restrict__ es) {
    int t = blockIdx.x & 7;
    int b = blockIdx.x >> 3;          // 0..31
    size_t bi = (size_t)t * GB + b;
    const unsigned char* h8 = hist8 + bi * N_NODES;
    const unsigned short* lr = lrow16 + bi * NPAIR;
    const int* bs = base + bi * NPAIR;
    const unsigned short* stg = stagedG + bi * CHUNK;
    const int* rw = row + t * N_NODES;
    for (int i = threadIdx.x; i < NPAIR; i += blockDim.x) {
        uchar2 c = *(const uchar2*)(h8 + 2 * i);
        int l0 = lr[i];
        int l1 = l0 + c.x;
        int bp = bs[i];
        int b0 = bp & 0xffff, b1 = (bp >> 16) & 0xffff;
        int2 rr = *(const int2*)(rw + 2 * i);
        for (int k = 0; k < c.x; ++k) es[rr.x + b0 + k] = stg[l0 + k];
        for (int k = 0; k < c.y; ++k) es[rr.y + b1 + k] = stg[l1 + k];
    }
}

// ---- GAT1 reduce: ONE THREAD per (t,dst) bin; ushort4 es loads + unroll-4 ----
__global__ void k_gat1red(const unsigned short* __restrict__ es, const int* __restrict__ row,
                          const float* __restrict__ x, const float* __restrict__ S4,
                          float* __restrict__ inv) {
    int wid = blockIdx.x * 256 + threadIdx.x;  // grid exact: 625*256 == TN
    int t = wid / N_NODES;
    int start = row[wid], end = row[wid + 1];
    float Ss0 = S4[0], Ss1 = S4[1], Sd0 = S4[2], Sd1 = S4[3];
    float xd = x[wid];
    float a0 = xd * Sd0, a1 = xd * Sd1;
    const float* xt = x + (size_t)t * N_NODES;
    // self-loop init
    float w0 = __expf(lrelu02(fmaf(xd, Ss0, a0))), w1 = __expf(lrelu02(fmaf(xd, Ss1, a1)));
    float d0 = w0, n0 = w0 * xd, d1 = w1, n1 = w1 * xd;

#define G1E(xs) { \
    float v0 = __expf(lrelu02(fmaf(xs, Ss0, a0))); \
    float v1 = __expf(lrelu02(fmaf(xs, Ss1, a1))); \
    d0 += v0; n0 = fmaf(v0, xs, n0); \
    d1 += v1; n1 = fmaf(v1, xs, n1); }

    int p = start;
    {
        int nh = (4 - (start & 3)) & 3;
        if (nh > end - start) nh = end - start;
        if (nh > 0) {
            float xa = xt[es[p]];
            float xb = (nh > 1) ? xt[es[p + 1]] : 0.f;
            float xc = (nh > 2) ? xt[es[p + 2]] : 0.f;
            G1E(xa)
            if (nh > 1) G1E(xb)
            if (nh > 2) G1E(xc)
            p += nh;
        }
    }
    for (; p + 3 < end; p += 4) {
        ushort4 e4 = *(const ushort4*)(es + p);
        float xa = xt[e4.x], xb = xt[e4.y], xc = xt[e4.z], xe = xt[e4.w];
        float va0 = __expf(lrelu02(fmaf(xa, Ss0, a0)));
        float va1 = __expf(lrelu02(fmaf(xa, Ss1, a1)));
        float vb0 = __expf(lrelu02(fmaf(xb, Ss0, a0)));
        float vb1 = __expf(lrelu02(fmaf(xb, Ss1, a1)));
        float vc0 = __expf(lrelu02(fmaf(xc, Ss0, a0)));
        float vc1 = __expf(lrelu02(fmaf(xc, Ss1, a1)));
        float ve0 = __expf(lrelu02(fmaf(xe, Ss0, a0)));
        float ve1 = __expf(lrelu02(fmaf(xe, Ss1, a1)));
        d0 += va0 + vb0 + vc0 + ve0;
        d1 += va1 + vb1 + vc1 + ve1;
        n0 = fmaf(va0, xa, fmaf(vb0, xb, fmaf(vc0, xc, fmaf(ve0, xe, n0))));
        n1 = fmaf(va1, xa, fmaf(vb1, xb, fmaf(vc1, xc, fmaf(ve1, xe, n1))));
    }
    {
        int nt = end - p;
        if (nt > 0) {
            float xa = xt[es[p]];
            float xb = (nt > 1) ? xt[es[p + 1]] : 0.f;
            float xc = (nt > 2) ? xt[es[p + 2]] : 0.f;
            G1E(xa)
            if (nt > 1) G1E(xb)
            if (nt > 2) G1E(xc)
        }
    }
#undef G1E
    inv[(size_t)wid * 2 + 0] = n0 / (d0 + 1e-16f);
    inv[(size_t)wid * 2 + 1] = n1 / (d1 + 1e-16f);
}

// ---- GAT1 epilogue + h2 = elu(z1) @ W2, FP16 dot2 matvec ----
__global__ void k_node1(const float* __restrict__ inv, const float* __restrict__ W1,
                        const float* __restrict__ b1, const float* __restrict__ W2,
                        const float* __restrict__ as2w, const float* __restrict__ ad2w,
                        __half* __restrict__ h2h, __half* __restrict__ sh,
                        float* __restrict__ ad2) {
    __shared__ float sW1[HEADS * HDIM];
    __shared__ float sb1[HEADS * HDIM];
    __shared__ __half sW2T[HDIM * 64];        // [c][k], swizzled chunks
    __shared__ float sas[HDIM], sad[HDIM];
    __shared__ __half z1h[NPB][HEADS * HDIM]; // [8][64] fp16

    for (int i = threadIdx.x; i < HEADS * HDIM; i += blockDim.x) {
        sW1[i] = W1[i];
        sb1[i] = b1[i];
    }
    for (int i = threadIdx.x; i < HEADS * HDIM * HDIM; i += blockDim.x) {
        int k = i >> 5, c = i & 31;
        int j = k >> 2;                       // true chunk
        int js = j ^ (c & 15);                // stored chunk slot
        sW2T[c * 64 + (js << 2) + (k & 3)] = __float2half_rn(W2[i]);
    }
    for (int i = threadIdx.x; i < HDIM; i += blockDim.x) {
        sas[i] = as2w[i];
        sad[i] = ad2w[i];
    }
    __syncthreads();

    int ln = threadIdx.x >> 5;
    int c = threadIdx.x & 31;
    int tn = blockIdx.x * NPB + ln;
    if (tn >= TN) return;

    float inv0 = inv[(size_t)tn * 2 + 0];
    float inv1 = inv[(size_t)tn * 2 + 1];
    z1h[ln][c] = __float2half_rn(eluf(inv0 * sW1[c] + sb1[c]));
    z1h[ln][HDIM + c] = __float2half_rn(eluf(inv1 * sW1[HDIM + c] + sb1[HDIM + c]));
    __syncthreads();

    float acc = 0.f;
    const int key = c & 15;
#pragma unroll
    for (int j = 0; j < 16; ++j) {
        uint2 w = *(const uint2*)&sW2T[c * 64 + ((j ^ key) << 2)];
        uint2 z = *(const uint2*)&z1h[ln][j << 2];
        acc = dot4h(w, z, acc);
    }

    h2h[(size_t)tn * HDIM + c] = __float2half_rn(acc);
    float s = lane32_sum(acc * sas[c]);
    float d = lane32_sum(acc * sad[c]);
    if (c == 0) {
        sh[tn] = __float2half_rn(s);   // src logit (fp16)
        ad2[tn] = d;
    }
}

// ---- GAT2 reduce: 16 nodes x 4 lanes x 8 channels (round-24 re-tile).
// Per iteration: 2 loads + 8 cvt + 5 w + 8 fma advancing 16 edges
// (1.56 inst/edge vs 2.0 in the 8x8 tile); h2 row read as one 16B uint4.
// acc fp32 (w can reach e^10: fp16 acc would overflow).
__global__ void k_gat2red(const unsigned short* __restrict__ es, const int* __restrict__ row,
                          const __half* __restrict__ sh, const float* __restrict__ ad2,
                          const __half* __restrict__ h2h, const float* __restrict__ b2,
                          __half* __restrict__ z2h) {
    int b = blockIdx.x;
    int t = b & 7;             // XCD pin
    int chunk = b >> 3;        // 0..1249
    int lane = threadIdx.x;    // block = 64 threads = 1 wave
    int u = lane >> 2;         // node slot 0..15
    int l = lane & 3;          // channel octet: channels 8l..8l+7
    int node = chunk * 16 + u; // exact: 1250*16 == 20000
    int wid = t * N_NODES + node;

    int start = row[wid], end = row[wid + 1];
    float ad = ad2[wid];
    const __half* sht = sh + (size_t)t * N_NODES;
    const __half* h2t = h2h + (size_t)t * N_NODES * HDIM;

    float4 a0 = make_float4(0.f, 0.f, 0.f, 0.f);
    float4 a1 = make_float4(0.f, 0.f, 0.f, 0.f);
    float den = 0.f;

#define G2E(sv) { \
    float w = __expf(lrelu02(__half2float(sht[sv]) + ad)); \
    float4 ha, hb; \
    ldh8(h2t + (size_t)(sv) * HDIM + 8 * l, ha, hb); \
    a0.x = fmaf(w, ha.x, a0.x); a0.y = fmaf(w, ha.y, a0.y); \
    a0.z = fmaf(w, ha.z, a0.z); a0.w = fmaf(w, ha.w, a0.w); \
    a1.x = fmaf(w, hb.x, a1.x); a1.y = fmaf(w, hb.y, a1.y); \
    a1.z = fmaf(w, hb.z, a1.z); a1.w = fmaf(w, hb.w, a1.w); \
    den += w; }

    int p = start;
    // head: align p to 4
    {
        int nh = (4 - (start & 3)) & 3;
        if (nh > end - start) nh = end - start;
        if (nh > 0) {
            int sh0 = es[p];
            int sh1 = (nh > 1) ? es[p + 1] : 0;
            int sh2 = (nh > 2) ? es[p + 2] : 0;
            G2E(sh0)
            if (nh > 1) G2E(sh1)
            if (nh > 2) G2E(sh2)
            p += nh;
        }
    }
    // main: 4 edges per iteration (one ushort4; 4 independent 16B gathers)
    for (; p + 3 < end; p += 4) {
        ushort4 eA = *(const ushort4*)(es + p);
        int s0 = eA.x, s1 = eA.y, s2 = eA.z, s3 = eA.w;
        float v0 = __half2float(sht[s0]), v1 = __half2float(sht[s1]);
        float v2 = __half2float(sht[s2]), v3 = __half2float(sht[s3]);
        float4 h0a, h0b, h1a, h1b, h2a, h2b, h3a, h3b;
        ldh8(h2t + (size_t)s0 * HDIM + 8 * l, h0a, h0b);
        ldh8(h2t + (size_t)s1 * HDIM + 8 * l, h1a, h1b);
        ldh8(h2t + (size_t)s2 * HDIM + 8 * l, h2a, h2b);
        ldh8(h2t + (size_t)s3 * HDIM + 8 * l, h3a, h3b);
        float w0 = __expf(lrelu02(v0 + ad));
        float w1 = __expf(lrelu02(v1 + ad));
        float w2 = __expf(lrelu02(v2 + ad));
        float w3 = __expf(lrelu02(v3 + ad));
        a0.x = fmaf(w0, h0a.x, fmaf(w1, h1a.x, fmaf(w2, h2a.x, fmaf(w3, h3a.x, a0.x))));
        a0.y = fmaf(w0, h0a.y, fmaf(w1, h1a.y, fmaf(w2, h2a.y, fmaf(w3, h3a.y, a0.y))));
        a0.z = fmaf(w0, h0a.z, fmaf(w1, h1a.z, fmaf(w2, h2a.z, fmaf(w3, h3a.z, a0.z))));
        a0.w = fmaf(w0, h0a.w, fmaf(w1, h1a.w, fmaf(w2, h2a.w, fmaf(w3, h3a.w, a0.w))));
        a1.x = fmaf(w0, h0b.x, fmaf(w1, h1b.x, fmaf(w2, h2b.x, fmaf(w3, h3b.x, a1.x))));
        a1.y = fmaf(w0, h0b.y, fmaf(w1, h1b.y, fmaf(w2, h2b.y, fmaf(w3, h3b.y, a1.y))));
        a1.z = fmaf(w0, h0b.z, fmaf(w1, h1b.z, fmaf(w2, h2b.z, fmaf(w3, h3b.z, a1.z))));
        a1.w = fmaf(w0, h0b.w, fmaf(w1, h1b.w, fmaf(w2, h2b.w, fmaf(w3, h3b.w, a1.w))));
        den += w0 + w1 + w2 + w3;
    }
    // tail: <=3 scalar
    {
        int nt = end - p;
        if (nt > 0) {
            int st0 = es[p];
            int st1 = (nt > 1) ? es[p + 1] : 0;
            int st2 = (nt > 2) ? es[p + 2] : 0;
            G2E(st0)
            if (nt > 1) G2E(st1)
            if (nt > 2) G2E(st2)
        }
    }
    // self-loop
    G2E(node)
#undef G2E

    float invd = 1.f / (den + 1e-16f);
    float4 bb0 = *(const float4*)(b2 + 8 * l);
    float4 bb1 = *(const float4*)(b2 + 8 * l + 4);
    __half o0 = __float2half_rn(eluf(fmaf(a0.x, invd, bb0.x)));
    __half o1 = __float2half_rn(eluf(fmaf(a0.y, invd, bb0.y)));
    __half o2 = __float2half_rn(eluf(fmaf(a0.z, invd, bb0.z)));
    __half o3 = __float2half_rn(eluf(fmaf(a0.w, invd, bb0.w)));
    __half o4 = __float2half_rn(eluf(fmaf(a1.x, invd, bb1.x)));
    __half o5 = __float2half_rn(eluf(fmaf(a1.y, invd, bb1.y)));
    __half o6 = __float2half_rn(eluf(fmaf(a1.z, invd, bb1.z)));
    __half o7 = __float2half_rn(eluf(fmaf(a1.w, invd, bb1.w)));
    ushort4 pk0, pk1;
    pk0.x = *(unsigned short*)&o0; pk0.y = *(unsigned short*)&o1;
    pk0.z = *(unsigned short*)&o2; pk0.w = *(unsigned short*)&o3;
    pk1.x = *(unsigned short*)&o4; pk1.y = *(unsigned short*)&o5;
    pk1.z = *(unsigned short*)&o6; pk1.w = *(unsigned short*)&o7;
    *(ushort4*)(z2h + (size_t)wid * HDIM + 8 * l) = pk0;
    *(ushort4*)(z2h + (size_t)wid * HDIM + 8 * l + 4) = pk1;
}

// ---- fused 8-step GRU + output projection, FP16 weights + v_dot2_f32_f16 ----
__global__ void k_gru_all(const __half* __restrict__ z2h, const float* __restrict__ Wih,
                          const float* __restrict__ Whh, const float* __restrict__ bih,
                          const float* __restrict__ bhh, const float* __restrict__ Wout,
                          const float* __restrict__ bout, float* __restrict__ out) {
    __shared__ __half sWih[3 * HDIM * 32];  // 6 KB, swizzled
    __shared__ __half sWhh[3 * HDIM * 32];
    __shared__ float sbih[3 * HDIM], sbhh[3 * HDIM], sWout[HDIM];
    __shared__ __half hls[GNB * 32];        // 1 KB
    __shared__ __half zls[GNB * 32];

    for (int i = threadIdx.x; i < 3 * HDIM * HDIM; i += 256) {
        int r = i >> 5, cc = i & 31;
        int key = (r ^ (r >> 3)) & 7;
        int pos = r * 32 + ((((cc >> 2) ^ key) << 2) | (cc & 3));
        sWih[pos] = __float2half_rn(Wih[i]);
        sWhh[pos] = __float2half_rn(Whh[i]);
    }
    for (int i = threadIdx.x; i < 3 * HDIM; i += 256) {
        sbih[i] = bih[i];
        sbhh[i] = bhh[i];
    }
    for (int i = threadIdx.x; i < HDIM; i += 256) sWout[i] = Wout[i];
    for (int i = threadIdx.x; i < GNB * 32; i += 256) hls[i] = __float2half_rn(0.f);
    __syncthreads();

    const int c = threadIdx.x & 31;
    const int nb = (threadIdx.x >> 5) * GNT;
    const int gbase = blockIdx.x * GNB;
    const int rR = c, rZ = HDIM + c, rN = 2 * HDIM + c;
    const int kR = (rR ^ (rR >> 3)) & 7;
    const int kZ = (rZ ^ (rZ >> 3)) & 7;
    const int kN = (rN ^ (rN >> 3)) & 7;

    const float br = sbih[c], bz = sbih[HDIM + c], bn = sbih[2 * HDIM + c];
    const float cr = sbhh[c], cz = sbhh[HDIM + c], cn = sbhh[2 * HDIM + c];

    float air0, aiz0, ain0, ahr0, ahz0, ahn0, hr0;
    float air1, aiz1, ain1, ahr1, ahz1, ahn1, hr1;
    hr0 = hr1 = 0.f;

    for (int t = 0; t < T_STEPS; ++t) {
        const uint2* zsrc = (const uint2*)(z2h + ((size_t)t * N_NODES + gbase) * HDIM);
        if (threadIdx.x < GNB * 8)
            *(uint2*)&zls[threadIdx.x * 4] = zsrc[threadIdx.x];
        __syncthreads();

        air0 = air1 = br;
        aiz0 = aiz1 = bz;
        ain0 = ain1 = bn;
        ahr0 = ahr1 = cr;
        ahz0 = ahz1 = cz;
        ahn0 = ahn1 = cn;
#pragma unroll 2
        for (int q = 0; q < 8; ++q) {
            int kq = q << 2;
            uint2 wri = *(const uint2*)&sWih[rR * 32 + ((q ^ kR) << 2)];
            uint2 wzi = *(const uint2*)&sWih[rZ * 32 + ((q ^ kZ) << 2)];
            uint2 wni = *(const uint2*)&sWih[rN * 32 + ((q ^ kN) << 2)];
            uint2 wrh = *(const uint2*)&sWhh[rR * 32 + ((q ^ kR) << 2)];
            uint2 wzh = *(const uint2*)&sWhh[rZ * 32 + ((q ^ kZ) << 2)];
            uint2 wnh = *(const uint2*)&sWhh[rN * 32 + ((q ^ kN) << 2)];
            uint2 zv0 = *(const uint2*)&zls[(nb + 0) * 32 + kq];
            uint2 hv0 = *(const uint2*)&hls[(nb + 0) * 32 + kq];
            uint2 zv1 = *(const uint2*)&zls[(nb + 1) * 32 + kq];
            uint2 hv1 = *(const uint2*)&hls[(nb + 1) * 32 + kq];
            air0 = dot4h(wri, zv0, air0);
            aiz0 = dot4h(wzi, zv0, aiz0);
            ain0 = dot4h(wni, zv0, ain0);
            ahr0 = dot4h(wrh, hv0, ahr0);
            ahz0 = dot4h(wzh, hv0, ahz0);
            ahn0 = dot4h(wnh, hv0, ahn0);
            air1 = dot4h(wri, zv1, air1);
            aiz1 = dot4h(wzi, zv1, aiz1);
            ain1 = dot4h(wni, zv1, ain1);
            ahr1 = dot4h(wrh, hv1, ahr1);
            ahz1 = dot4h(wzh, hv1, ahz1);
            ahn1 = dot4h(wnh, hv1, ahn1);
        }
        {
            float r = fsig(air0 + ahr0);
            float z = fsig(aiz0 + ahz0);
            float g = ftanh(ain0 + r * ahn0);
            hr0 = (1.f - z) * g + z * hr0;
            hls[(nb + 0) * 32 + c] = __float2half_rn(hr0);
        }
        {
            float r = fsig(air1 + ahr1);
            float z = fsig(aiz1 + ahz1);
            float g = ftanh(ain1 + r * ahn1);
            hr1 = (1.f - z) * g + z * hr1;
            hls[(nb + 1) * 32 + c] = __float2half_rn(hr1);
        }
        __syncthreads();
    }

    float wo = sWout[c];
    float s0 = lane32_sum(hr0 * wo);
    float s1 = lane32_sum(hr1 * wo);
    if (c == 0) {
        float bo = bout[0];
        out[gbase + nb + 0] = s0 + bo;
        out[gbase + nb + 1] = s1 + bo;
    }
}

extern "C" void kernel_launch(void* const* d_in, const int* in_sizes, int n_in,
                              void* d_out, int out_size, void* d_ws, size_t ws_size,
                              hipStream_t stream) {
    const float* x      = (const float*)d_in[0];   // T*N
    const int* eidx     = (const int*)d_in[1];     // T*2*E
    const float* W1     = (const float*)d_in[2];
    const float* a_src1 = (const float*)d_in[3];
    const float* a_dst1 = (const float*)d_in[4];
    const float* b1     = (const float*)d_in[5];
    const float* W2     = (const float*)d_in[6];
    const float* a_src2 = (const float*)d_in[7];
    const float* a_dst2 = (const float*)d_in[8];
    const float* b2     = (const float*)d_in[9];
    const float* W_ih   = (const float*)d_in[10];
    const float* W_hh   = (const float*)d_in[11];
    const float* b_ih   = (const float*)d_in[12];
    const float* b_hh   = (const float*)d_in[13];
    const float* W_out  = (const float*)d_in[14];
    const float* b_out  = (const float*)d_in[15];
    float* out = (float*)d_out;

    char* base_ws = (char*)d_ws;
    size_t off = 0;
    auto alloc = [&](size_t bytes) {
        char* p = base_ws + off;
        off = (off + bytes + 15) & ~(size_t)15;
        return p;
    };
    int* cnt             = (int*)alloc((size_t)TN * 4);
    int* row             = (int*)alloc((size_t)(TN + 1) * 4);
    int* bsum            = (int*)alloc((size_t)SCAN_BLOCKS * 4);
    int* bpre            = (int*)alloc((size_t)SCAN_BLOCKS * 4);
    float* inv           = (float*)alloc((size_t)TN * 2 * 4);
    __half* h2h          = (__half*)alloc((size_t)TN * HDIM * 2);   // 10.24 MB
    __half* sh           = (__half*)alloc((size_t)TN * 2);          // 320 KB
    float* ad2           = (float*)alloc((size_t)TN * 4);
    __half* z2h          = (__half*)alloc((size_t)TN * HDIM * 2);   // 10.24 MB
    float* S4            = (float*)alloc(16);
    unsigned short* es   = (unsigned short*)alloc((size_t)TE * 2);  // 10.24 MB
    int* bbase           = (int*)alloc((size_t)T_STEPS * GB * NPAIR * 4);   // 10.24 MB
    unsigned short* stagedG = (unsigned short*)alloc((size_t)TE * 2);       // 10.24 MB
    // Aliases (stream-order safe):
    //  h2h region = hist8 (5.12 MB u8) + lrow16 (5.12 MB u16): written by
    //  hist, read by blkpre/scatter; h2h written later by node1.
    unsigned char* hist8   = (unsigned char*)h2h;
    unsigned short* lrow16 = (unsigned short*)((char*)h2h + (size_t)T_STEPS * GB * N_NODES);

    const int B = 256;
    k_hist<<<8 * GB, 1024, 0, stream>>>(eidx, hist8, lrow16, stagedG);
    k_blkpre<<<(T_STEPS * NPAIR + B - 1) / B, B, 0, stream>>>(hist8, bbase, cnt,
                                                              W1, a_src1, a_dst1, S4);
    k_scan_a<<<SCAN_BLOCKS, B, 0, stream>>>(cnt, bsum);
    k_scan_b<<<1, B, 0, stream>>>(bsum, bpre);
    k_scan_c<<<SCAN_BLOCKS, B, 0, stream>>>(cnt, bpre, row);
    k_scatter<<<8 * GB, 512, 0, stream>>>(hist8, lrow16, row, bbase, stagedG, es);

    k_gat1red<<<TN / 256, B, 0, stream>>>(es, row, x, S4, inv);
    k_node1<<<TN / NPB, B, 0, stream>>>(inv, W1, b1, W2, a_src2, a_dst2, h2h, sh, ad2);
    k_gat2red<<<8 * (N_NODES / 16), 64, 0, stream>>>(es, row, sh, ad2, h2h, b2, z2h);

    k_gru_all<<<N_NODES / GNB, B, 0, stream>>>(z2h, W_ih, W_hh, b_ih, b_hh, W_out, b_out, out);
}

// Round 26
// 269.061 us; speedup vs baseline: 1.0159x; 1.0159x over previous
//
#include <hip/hip_runtime.h>
#include <hip/hip_fp16.h>
#include <math.h>

#define N_NODES 20000
#define T_STEPS 8
#define E_EDGES 640000
#define TN (T_STEPS * N_NODES)   // 160000
#define TE (T_STEPS * E_EDGES)   // 5120000
#define HDIM 32
#define HEADS 2
#define NPB 8                    // nodes per block for lane-parallel node kernels
#define SCAN_BLOCKS 625          // TN / 256 exactly
#define GB 32                    // histogram blocks per timestep
#define CHUNK (E_EDGES / GB)     // 20000 edges per histogram block
#define NPAIR (N_NODES / 2)      // packed bins per timestep
#define GNT 2                    // GRU nodes per thread-group
#define GNB (8 * GNT)            // GRU nodes per block = 16 (1250 blocks exactly)
#define G2NB 64                  // gat2red nodes per block (256 thr, 4 lanes/node)
#define G2BLK ((N_NODES + G2NB - 1) / G2NB)  // 313 blocks per timestep

typedef _Float16 h2v __attribute__((ext_vector_type(2)));

__device__ __forceinline__ float lrelu02(float v) { return fmaxf(v, 0.2f * v); }
__device__ __forceinline__ float eluf(float v) { return v > 0.f ? v : expm1f(v); }
__device__ __forceinline__ float fsig(float v) {
    return __fdividef(1.f, 1.f + __expf(-v));
}
__device__ __forceinline__ float ftanh(float v) {
    return 1.f - __fdividef(2.f, __expf(2.f * v) + 1.f);
}

__device__ __forceinline__ float lane32_sum(float v) {
    v += __shfl_xor(v, 16);
    v += __shfl_xor(v, 8);
    v += __shfl_xor(v, 4);
    v += __shfl_xor(v, 2);
    v += __shfl_xor(v, 1);
    return v;
}

// dot of 4 halves x 4 halves accumulated into f32 (2x v_dot2_f32_f16)
__device__ __forceinline__ float dot4h(uint2 a, uint2 b, float c) {
    h2v a0 = *(h2v*)&a.x, a1 = *(h2v*)&a.y;
    h2v b0 = *(h2v*)&b.x, b1 = *(h2v*)&b.y;
    return __builtin_amdgcn_fdot2(a0, b0, __builtin_amdgcn_fdot2(a1, b1, c, false), false);
}

// load 8 fp16 channels (16 B, one dwordx4) -> two float4
__device__ __forceinline__ void ldh8(const __half* p, float4& f0, float4& f1) {
    uint4 u = *(const uint4*)p;
    __half2 a = *(__half2*)&u.x;
    __half2 b = *(__half2*)&u.y;
    __half2 c = *(__half2*)&u.z;
    __half2 d = *(__half2*)&u.w;
    float2 fa = __half22float2(a), fb = __half22float2(b);
    float2 fc = __half22float2(c), fd = __half22float2(d);
    f0 = make_float4(fa.x, fa.y, fb.x, fb.y);
    f1 = make_float4(fc.x, fc.y, fd.x, fd.y);
}

// ---- pass A: per-block LDS histogram + local scan + locally-sorted staging ----
__global__ void k_hist(const int* __restrict__ ei, unsigned char* __restrict__ hist8,
                       unsigned short* __restrict__ lrow16,
                       unsigned short* __restrict__ stagedG) {
    __shared__ int lh[NPAIR];                 // 40 KB: counts -> packed lrow
    __shared__ unsigned short sdst[CHUNK];    // 40 KB
    __shared__ unsigned short ssrc[CHUNK];    // 40 KB
    __shared__ int partial[1024];             // 4 KB
    int t = blockIdx.x & 7, b = blockIdx.x >> 3;
    for (int i = threadIdx.x; i < NPAIR; i += 1024) lh[i] = 0;
    __syncthreads();
    const int* srcp = ei + (size_t)t * 2 * E_EDGES + b * CHUNK;
    const int* dstp = srcp + E_EDGES;
    for (int j = threadIdx.x; j < CHUNK; j += 1024) {
        int dst = dstp[j];
        int src = srcp[j];
        sdst[j] = (unsigned short)dst;
        ssrc[j] = (unsigned short)src;
        atomicAdd(&lh[dst >> 1], (dst & 1) ? 65536 : 1);
    }
    __syncthreads();
    size_t bi = (size_t)t * GB + b;
    unsigned char* hp = hist8 + bi * N_NODES;
    for (int i = threadIdx.x; i < NPAIR; i += 1024) {
        int v = lh[i];
        uchar2 pk;
        pk.x = (unsigned char)(v & 0xff);
        pk.y = (unsigned char)((v >> 16) & 0xff);
        *(uchar2*)(hp + 2 * i) = pk;
    }
    __syncthreads();
    const int tpp = 10;   // 1024*10 >= NPAIR
    int i0 = threadIdx.x * tpp;
    int run = 0;
    for (int k = 0; k < tpp; ++k) {
        int i = i0 + k;
        if (i < NPAIR) {
            int v = lh[i];
            run += (v & 0xffff) + (v >> 16);
        }
    }
    partial[threadIdx.x] = run;
    __syncthreads();
    for (int off = 1; off < 1024; off <<= 1) {
        int add = (threadIdx.x >= off) ? partial[threadIdx.x - off] : 0;
        __syncthreads();
        partial[threadIdx.x] += add;
        __syncthreads();
    }
    int run2 = (threadIdx.x > 0) ? partial[threadIdx.x - 1] : 0;
    for (int k = 0; k < tpp; ++k) {
        int i = i0 + k;
        if (i < NPAIR) {
            int v = lh[i];
            int c0 = v & 0xffff, c1 = v >> 16;
            lh[i] = run2 | ((run2 + c0) << 16);   // packed (l0, l1)
            run2 += c0 + c1;
        }
    }
    __syncthreads();
    unsigned short* lp = lrow16 + bi * NPAIR;
    for (int i = threadIdx.x; i < NPAIR; i += 1024)
        lp[i] = (unsigned short)(lh[i] & 0xffff);
    __syncthreads();   // all lrow reads of lh done before atomics mutate lh
    unsigned short* stg = stagedG + bi * CHUNK;
    for (int j = threadIdx.x; j < CHUNK; j += 1024) {
        int dst = sdst[j];
        int old = atomicAdd(&lh[dst >> 1], (dst & 1) ? 65536 : 1);
        int pos = (old >> (16 * (dst & 1))) & 0xffff;
        stg[pos] = ssrc[j];
    }
}

// ---- pass B: per-(t,dst) prefix over blocks -> base (packed) + totals ----
__global__ void k_blkpre(const unsigned char* __restrict__ hist8, int* __restrict__ base,
                         int* __restrict__ cnt, const float* __restrict__ W1,
                         const float* __restrict__ as1, const float* __restrict__ ad1,
                         float* __restrict__ S4) {
    int i = blockIdx.x * blockDim.x + threadIdx.x;  // (t, pair)
    if (i == 0) {
        for (int hd = 0; hd < HEADS; ++hd) {
            float ss = 0.f, sd = 0.f;
            for (int c = 0; c < HDIM; ++c) {
                ss += W1[hd * HDIM + c] * as1[hd * HDIM + c];
                sd += W1[hd * HDIM + c] * ad1[hd * HDIM + c];
            }
            S4[hd] = ss;
            S4[HEADS + hd] = sd;
        }
    }
    if (i >= T_STEPS * NPAIR) return;
    int t = i / NPAIR, pr = i % NPAIR;
    int a0 = 0, a1 = 0;
    for (int b = 0; b < GB; ++b) {
        size_t bi = ((size_t)t * GB + b);
        uchar2 v = *(const uchar2*)(hist8 + bi * N_NODES + 2 * pr);
        base[bi * NPAIR + pr] = a0 | (a1 << 16);
        a0 += v.x;
        a1 += v.y;
    }
    cnt[t * N_NODES + 2 * pr] = a0;
    cnt[t * N_NODES + 2 * pr + 1] = a1;
}

// ---- scan (exclusive) over cnt[TN] -> row[TN+1] ----
__global__ void k_scan_a(const int* __restrict__ cnt, int* __restrict__ bsum) {
    __shared__ int s[256];
    int i = blockIdx.x * 256 + threadIdx.x;
    s[threadIdx.x] = (i < TN) ? cnt[i] : 0;
    __syncthreads();
    for (int off = 128; off > 0; off >>= 1) {
        if (threadIdx.x < off) s[threadIdx.x] += s[threadIdx.x + off];
        __syncthreads();
    }
    if (threadIdx.x == 0) bsum[blockIdx.x] = s[0];
}

__global__ void k_scan_b(const int* __restrict__ bsum, int* __restrict__ bpre) {
    __shared__ int s[256];
    __shared__ int carry;
    if (threadIdx.x == 0) carry = 0;
    __syncthreads();
    for (int base = 0; base < SCAN_BLOCKS; base += 256) {
        int i = base + threadIdx.x;
        int v = (i < SCAN_BLOCKS) ? bsum[i] : 0;
        s[threadIdx.x] = v;
        __syncthreads();
        for (int off = 1; off < 256; off <<= 1) {
            int add = (threadIdx.x >= off) ? s[threadIdx.x - off] : 0;
            __syncthreads();
            s[threadIdx.x] += add;
            __syncthreads();
        }
        if (i < SCAN_BLOCKS) bpre[i] = carry + s[threadIdx.x] - v;  // exclusive
        __syncthreads();
        if (threadIdx.x == 0) carry += s[255];
        __syncthreads();
    }
}

__global__ void k_scan_c(const int* __restrict__ cnt, const int* __restrict__ bpre,
                         int* __restrict__ row) {
    __shared__ int s[256];
    int i = blockIdx.x * 256 + threadIdx.x;
    int v = (i < TN) ? cnt[i] : 0;
    s[threadIdx.x] = v;
    __syncthreads();
    for (int off = 1; off < 256; off <<= 1) {
        int add = (threadIdx.x >= off) ? s[threadIdx.x - off] : 0;
        __syncthreads();
        s[threadIdx.x] += add;
        __syncthreads();
    }
    if (i < TN) row[i] = bpre[blockIdx.x] + s[threadIdx.x] - v;
    if (blockIdx.x == 0 && threadIdx.x == 0) row[TN] = TE;
}

// ---- pass C: per-bin copy from locally-sorted staging into global CSR ----
__global__ void k_scatter(const unsigned char* __restrict__ hist8,
                          const unsigned short* __restrict__ lrow16,
                          const int* __restrict__ row, const int* __restrict__ base,
                          const unsigned short* __restrict__ stagedG,
                          unsigned short* __restrict__ es) {
    int t = blockIdx.x & 7;
    int b = blockIdx.x >> 3;          // 0..31
    size_t bi = (size_t)t * GB + b;
    const unsigned char* h8 = hist8 + bi * N_NODES;
    const unsigned short* lr = lrow16 + bi * NPAIR;
    const int* bs = base + bi * NPAIR;
    const unsigned short* stg = stagedG + bi * CHUNK;
    const int* rw = row + t * N_NODES;
    for (int i = threadIdx.x; i < NPAIR; i += blockDim.x) {
        uchar2 c = *(const uchar2*)(h8 + 2 * i);
        int l0 = lr[i];
        int l1 = l0 + c.x;
        int bp = bs[i];
        int b0 = bp & 0xffff, b1 = (bp >> 16) & 0xffff;
        int2 rr = *(const int2*)(rw + 2 * i);
        for (int k = 0; k < c.x; ++k) es[rr.x + b0 + k] = stg[l0 + k];
        for (int k = 0; k < c.y; ++k) es[rr.y + b1 + k] = stg[l1 + k];
    }
}

// ---- GAT1 reduce: ONE THREAD per (t,dst) bin; ushort4 es loads + unroll-4 ----
__global__ void k_gat1red(const unsigned short* __restrict__ es, const int* __restrict__ row,
                          const float* __restrict__ x, const float* __restrict__ S4,
                          float* __restrict__ inv) {
    int wid = blockIdx.x * 256 + threadIdx.x;  // grid exact: 625*256 == TN
    int t = wid / N_NODES;
    int start = row[wid], end = row[wid + 1];
    float Ss0 = S4[0], Ss1 = S4[1], Sd0 = S4[2], Sd1 = S4[3];
    float xd = x[wid];
    float a0 = xd * Sd0, a1 = xd * Sd1;
    const float* xt = x + (size_t)t * N_NODES;
    // self-loop init
    float w0 = __expf(lrelu02(fmaf(xd, Ss0, a0))), w1 = __expf(lrelu02(fmaf(xd, Ss1, a1)));
    float d0 = w0, n0 = w0 * xd, d1 = w1, n1 = w1 * xd;

#define G1E(xs) { \
    float v0 = __expf(lrelu02(fmaf(xs, Ss0, a0))); \
    float v1 = __expf(lrelu02(fmaf(xs, Ss1, a1))); \
    d0 += v0; n0 = fmaf(v0, xs, n0); \
    d1 += v1; n1 = fmaf(v1, xs, n1); }

    int p = start;
    {
        int nh = (4 - (start & 3)) & 3;
        if (nh > end - start) nh = end - start;
        if (nh > 0) {
            float xa = xt[es[p]];
            float xb = (nh > 1) ? xt[es[p + 1]] : 0.f;
            float xc = (nh > 2) ? xt[es[p + 2]] : 0.f;
            G1E(xa)
            if (nh > 1) G1E(xb)
            if (nh > 2) G1E(xc)
            p += nh;
        }
    }
    for (; p + 3 < end; p += 4) {
        ushort4 e4 = *(const ushort4*)(es + p);
        float xa = xt[e4.x], xb = xt[e4.y], xc = xt[e4.z], xe = xt[e4.w];
        float va0 = __expf(lrelu02(fmaf(xa, Ss0, a0)));
        float va1 = __expf(lrelu02(fmaf(xa, Ss1, a1)));
        float vb0 = __expf(lrelu02(fmaf(xb, Ss0, a0)));
        float vb1 = __expf(lrelu02(fmaf(xb, Ss1, a1)));
        float vc0 = __expf(lrelu02(fmaf(xc, Ss0, a0)));
        float vc1 = __expf(lrelu02(fmaf(xc, Ss1, a1)));
        float ve0 = __expf(lrelu02(fmaf(xe, Ss0, a0)));
        float ve1 = __expf(lrelu02(fmaf(xe, Ss1, a1)));
        d0 += va0 + vb0 + vc0 + ve0;
        d1 += va1 + vb1 + vc1 + ve1;
        n0 = fmaf(va0, xa, fmaf(vb0, xb, fmaf(vc0, xc, fmaf(ve0, xe, n0))));
        n1 = fmaf(va1, xa, fmaf(vb1, xb, fmaf(vc1, xc, fmaf(ve1, xe, n1))));
    }
    {
        int nt = end - p;
        if (nt > 0) {
            float xa = xt[es[p]];
            float xb = (nt > 1) ? xt[es[p + 1]] : 0.f;
            float xc = (nt > 2) ? xt[es[p + 2]] : 0.f;
            G1E(xa)
            if (nt > 1) G1E(xb)
            if (nt > 2) G1E(xc)
        }
    }
#undef G1E
    inv[(size_t)wid * 2 + 0] = n0 / (d0 + 1e-16f);
    inv[(size_t)wid * 2 + 1] = n1 / (d1 + 1e-16f);
}

// ---- GAT1 epilogue + h2 = elu(z1) @ W2, FP16 dot2 matvec ----
__global__ void k_node1(const float* __restrict__ inv, const float* __restrict__ W1,
                        const float* __restrict__ b1, const float* __restrict__ W2,
                        const float* __restrict__ as2w, const float* __restrict__ ad2w,
                        __half* __restrict__ h2h, __half* __restrict__ sh,
                        float* __restrict__ ad2) {
    __shared__ float sW1[HEADS * HDIM];
    __shared__ float sb1[HEADS * HDIM];
    __shared__ __half sW2T[HDIM * 64];        // [c][k], swizzled chunks
    __shared__ float sas[HDIM], sad[HDIM];
    __shared__ __half z1h[NPB][HEADS * HDIM]; // [8][64] fp16

    for (int i = threadIdx.x; i < HEADS * HDIM; i += blockDim.x) {
        sW1[i] = W1[i];
        sb1[i] = b1[i];
    }
    for (int i = threadIdx.x; i < HEADS * HDIM * HDIM; i += blockDim.x) {
        int k = i >> 5, c = i & 31;
        int j = k >> 2;                       // true chunk
        int js = j ^ (c & 15);                // stored chunk slot
        sW2T[c * 64 + (js << 2) + (k & 3)] = __float2half_rn(W2[i]);
    }
    for (int i = threadIdx.x; i < HDIM; i += blockDim.x) {
        sas[i] = as2w[i];
        sad[i] = ad2w[i];
    }
    __syncthreads();

    int ln = threadIdx.x >> 5;
    int c = threadIdx.x & 31;
    int tn = blockIdx.x * NPB + ln;
    if (tn >= TN) return;

    float inv0 = inv[(size_t)tn * 2 + 0];
    float inv1 = inv[(size_t)tn * 2 + 1];
    z1h[ln][c] = __float2half_rn(eluf(inv0 * sW1[c] + sb1[c]));
    z1h[ln][HDIM + c] = __float2half_rn(eluf(inv1 * sW1[HDIM + c] + sb1[HDIM + c]));
    __syncthreads();

    float acc = 0.f;
    const int key = c & 15;
#pragma unroll
    for (int j = 0; j < 16; ++j) {
        uint2 w = *(const uint2*)&sW2T[c * 64 + ((j ^ key) << 2)];
        uint2 z = *(const uint2*)&z1h[ln][j << 2];
        acc = dot4h(w, z, acc);
    }

    h2h[(size_t)tn * HDIM + c] = __float2half_rn(acc);
    float s = lane32_sum(acc * sas[c]);
    float d = lane32_sum(acc * sad[c]);
    if (c == 0) {
        sh[tn] = __float2half_rn(s);   // src logit (fp16)
        ad2[tn] = d;
    }
}

// ---- GAT2 reduce: 256 threads = 64 nodes x 4 lanes x 8 channels.
// Round-25 lesson: re-tile inst reduction was null (not VALU-bound); the
// sht logit table (40 KB/t) exceeds L1 (32 KB) -> per-edge logit gather
// thrashes. Stage the FULL timestep logit table in LDS (40 KB/block):
// per edge, only ONE random memory request remains (the h2 row).
__global__ void k_gat2red(const unsigned short* __restrict__ es, const int* __restrict__ row,
                          const __half* __restrict__ sh, const float* __restrict__ ad2,
                          const __half* __restrict__ h2h, const float* __restrict__ b2,
                          __half* __restrict__ z2h) {
    __shared__ __half shl[N_NODES];   // 40 KB: full logit table for timestep t
    int b = blockIdx.x;
    int t = b & 7;             // XCD pin
    int chunk = b >> 3;        // 0..312
    const __half* sht = sh + (size_t)t * N_NODES;
    // stage logits (coalesced uint4: 2500 x 16B)
    for (int i = threadIdx.x; i < N_NODES / 8; i += 256)
        *(uint4*)&shl[i * 8] = *(const uint4*)&sht[i * 8];
    __syncthreads();

    int u = threadIdx.x >> 2;  // node slot 0..63
    int l = threadIdx.x & 3;   // channel octet: channels 8l..8l+7
    int node = chunk * G2NB + u;
    if (node >= N_NODES) return;
    int wid = t * N_NODES + node;

    int start = row[wid], end = row[wid + 1];
    float ad = ad2[wid];
    const __half* h2t = h2h + (size_t)t * N_NODES * HDIM;

    float4 a0 = make_float4(0.f, 0.f, 0.f, 0.f);
    float4 a1 = make_float4(0.f, 0.f, 0.f, 0.f);
    float den = 0.f;

#define G2E(sv) { \
    float w = __expf(lrelu02(__half2float(shl[sv]) + ad)); \
    float4 ha, hb; \
    ldh8(h2t + (size_t)(sv) * HDIM + 8 * l, ha, hb); \
    a0.x = fmaf(w, ha.x, a0.x); a0.y = fmaf(w, ha.y, a0.y); \
    a0.z = fmaf(w, ha.z, a0.z); a0.w = fmaf(w, ha.w, a0.w); \
    a1.x = fmaf(w, hb.x, a1.x); a1.y = fmaf(w, hb.y, a1.y); \
    a1.z = fmaf(w, hb.z, a1.z); a1.w = fmaf(w, hb.w, a1.w); \
    den += w; }

    int p = start;
    // head: align p to 4
    {
        int nh = (4 - (start & 3)) & 3;
        if (nh > end - start) nh = end - start;
        if (nh > 0) {
            int sh0 = es[p];
            int sh1 = (nh > 1) ? es[p + 1] : 0;
            int sh2 = (nh > 2) ? es[p + 2] : 0;
            G2E(sh0)
            if (nh > 1) G2E(sh1)
            if (nh > 2) G2E(sh2)
            p += nh;
        }
    }
    // main: 4 edges per iteration (one ushort4; 4 independent 16B gathers)
    for (; p + 3 < end; p += 4) {
        ushort4 eA = *(const ushort4*)(es + p);
        int s0 = eA.x, s1 = eA.y, s2 = eA.z, s3 = eA.w;
        float v0 = __half2float(shl[s0]), v1 = __half2float(shl[s1]);
        float v2 = __half2float(shl[s2]), v3 = __half2float(shl[s3]);
        float4 h0a, h0b, h1a, h1b, h2a, h2b, h3a, h3b;
        ldh8(h2t + (size_t)s0 * HDIM + 8 * l, h0a, h0b);
        ldh8(h2t + (size_t)s1 * HDIM + 8 * l, h1a, h1b);
        ldh8(h2t + (size_t)s2 * HDIM + 8 * l, h2a, h2b);
        ldh8(h2t + (size_t)s3 * HDIM + 8 * l, h3a, h3b);
        float w0 = __expf(lrelu02(v0 + ad));
        float w1 = __expf(lrelu02(v1 + ad));
        float w2 = __expf(lrelu02(v2 + ad));
        float w3 = __expf(lrelu02(v3 + ad));
        a0.x = fmaf(w0, h0a.x, fmaf(w1, h1a.x, fmaf(w2, h2a.x, fmaf(w3, h3a.x, a0.x))));
        a0.y = fmaf(w0, h0a.y, fmaf(w1, h1a.y, fmaf(w2, h2a.y, fmaf(w3, h3a.y, a0.y))));
        a0.z = fmaf(w0, h0a.z, fmaf(w1, h1a.z, fmaf(w2, h2a.z, fmaf(w3, h3a.z, a0.z))));
        a0.w = fmaf(w0, h0a.w, fmaf(w1, h1a.w, fmaf(w2, h2a.w, fmaf(w3, h3a.w, a0.w))));
        a1.x = fmaf(w0, h0b.x, fmaf(w1, h1b.x, fmaf(w2, h2b.x, fmaf(w3, h3b.x, a1.x))));
        a1.y = fmaf(w0, h0b.y, fmaf(w1, h1b.y, fmaf(w2, h2b.y, fmaf(w3, h3b.y, a1.y))));
        a1.z = fmaf(w0, h0b.z, fmaf(w1, h1b.z, fmaf(w2, h2b.z, fmaf(w3, h3b.z, a1.z))));
        a1.w = fmaf(w0, h0b.w, fmaf(w1, h1b.w, fmaf(w2, h2b.w, fmaf(w3, h3b.w, a1.w))));
        den += w0 + w1 + w2 + w3;
    }
    // tail: <=3 scalar
    {
        int nt = end - p;
        if (nt > 0) {
            int st0 = es[p];
            int st1 = (nt > 1) ? es[p + 1] : 0;
            int st2 = (nt > 2) ? es[p + 2] : 0;
            G2E(st0)
            if (nt > 1) G2E(st1)
            if (nt > 2) G2E(st2)
        }
    }
    // self-loop
    G2E(node)
#undef G2E

    float invd = 1.f / (den + 1e-16f);
    float4 bb0 = *(const float4*)(b2 + 8 * l);
    float4 bb1 = *(const float4*)(b2 + 8 * l + 4);
    __half o0 = __float2half_rn(eluf(fmaf(a0.x, invd, bb0.x)));
    __half o1 = __float2half_rn(eluf(fmaf(a0.y, invd, bb0.y)));
    __half o2 = __float2half_rn(eluf(fmaf(a0.z, invd, bb0.z)));
    __half o3 = __float2half_rn(eluf(fmaf(a0.w, invd, bb0.w)));
    __half o4 = __float2half_rn(eluf(fmaf(a1.x, invd, bb1.x)));
    __half o5 = __float2half_rn(eluf(fmaf(a1.y, invd, bb1.y)));
    __half o6 = __float2half_rn(eluf(fmaf(a1.z, invd, bb1.z)));
    __half o7 = __float2half_rn(eluf(fmaf(a1.w, invd, bb1.w)));
    ushort4 pk0, pk1;
    pk0.x = *(unsigned short*)&o0; pk0.y = *(unsigned short*)&o1;
    pk0.z = *(unsigned short*)&o2; pk0.w = *(unsigned short*)&o3;
    pk1.x = *(unsigned short*)&o4; pk1.y = *(unsigned short*)&o5;
    pk1.z = *(unsigned short*)&o6; pk1.w = *(unsigned short*)&o7;
    *(ushort4*)(z2h + (size_t)wid * HDIM + 8 * l) = pk0;
    *(ushort4*)(z2h + (size_t)wid * HDIM + 8 * l + 4) = pk1;
}

// ---- fused 8-step GRU + output projection, FP16 weights + v_dot2_f32_f16 ----
__global__ void k_gru_all(const __half* __restrict__ z2h, const float* __restrict__ Wih,
                          const float* __restrict__ Whh, const float* __restrict__ bih,
                          const float* __restrict__ bhh, const float* __restrict__ Wout,
                          const float* __restrict__ bout, float* __restrict__ out) {
    __shared__ __half sWih[3 * HDIM * 32];  // 6 KB, swizzled
    __shared__ __half sWhh[3 * HDIM * 32];
    __shared__ float sbih[3 * HDIM], sbhh[3 * HDIM], sWout[HDIM];
    __shared__ __half hls[GNB * 32];        // 1 KB
    __shared__ __half zls[GNB * 32];

    for (int i = threadIdx.x; i < 3 * HDIM * HDIM; i += 256) {
        int r = i >> 5, cc = i & 31;
        int key = (r ^ (r >> 3)) & 7;
        int pos = r * 32 + ((((cc >> 2) ^ key) << 2) | (cc & 3));
        sWih[pos] = __float2half_rn(Wih[i]);
        sWhh[pos] = __float2half_rn(Whh[i]);
    }
    for (int i = threadIdx.x; i < 3 * HDIM; i += 256) {
        sbih[i] = bih[i];
        sbhh[i] = bhh[i];
    }
    for (int i = threadIdx.x; i < HDIM; i += 256) sWout[i] = Wout[i];
    for (int i = threadIdx.x; i < GNB * 32; i += 256) hls[i] = __float2half_rn(0.f);
    __syncthreads();

    const int c = threadIdx.x & 31;
    const int nb = (threadIdx.x >> 5) * GNT;
    const int gbase = blockIdx.x * GNB;
    const int rR = c, rZ = HDIM + c, rN = 2 * HDIM + c;
    const int kR = (rR ^ (rR >> 3)) & 7;
    const int kZ = (rZ ^ (rZ >> 3)) & 7;
    const int kN = (rN ^ (rN >> 3)) & 7;

    const float br = sbih[c], bz = sbih[HDIM + c], bn = sbih[2 * HDIM + c];
    const float cr = sbhh[c], cz = sbhh[HDIM + c], cn = sbhh[2 * HDIM + c];

    float air0, aiz0, ain0, ahr0, ahz0, ahn0, hr0;
    float air1, aiz1, ain1, ahr1, ahz1, ahn1, hr1;
    hr0 = hr1 = 0.f;

    for (int t = 0; t < T_STEPS; ++t) {
        const uint2* zsrc = (const uint2*)(z2h + ((size_t)t * N_NODES + gbase) * HDIM);
        if (threadIdx.x < GNB * 8)
            *(uint2*)&zls[threadIdx.x * 4] = zsrc[threadIdx.x];
        __syncthreads();

        air0 = air1 = br;
        aiz0 = aiz1 = bz;
        ain0 = ain1 = bn;
        ahr0 = ahr1 = cr;
        ahz0 = ahz1 = cz;
        ahn0 = ahn1 = cn;
#pragma unroll 2
        for (int q = 0; q < 8; ++q) {
            int kq = q << 2;
            uint2 wri = *(const uint2*)&sWih[rR * 32 + ((q ^ kR) << 2)];
            uint2 wzi = *(const uint2*)&sWih[rZ * 32 + ((q ^ kZ) << 2)];
            uint2 wni = *(const uint2*)&sWih[rN * 32 + ((q ^ kN) << 2)];
            uint2 wrh = *(const uint2*)&sWhh[rR * 32 + ((q ^ kR) << 2)];
            uint2 wzh = *(const uint2*)&sWhh[rZ * 32 + ((q ^ kZ) << 2)];
            uint2 wnh = *(const uint2*)&sWhh[rN * 32 + ((q ^ kN) << 2)];
            uint2 zv0 = *(const uint2*)&zls[(nb + 0) * 32 + kq];
            uint2 hv0 = *(const uint2*)&hls[(nb + 0) * 32 + kq];
            uint2 zv1 = *(const uint2*)&zls[(nb + 1) * 32 + kq];
            uint2 hv1 = *(const uint2*)&hls[(nb + 1) * 32 + kq];
            air0 = dot4h(wri, zv0, air0);
            aiz0 = dot4h(wzi, zv0, aiz0);
            ain0 = dot4h(wni, zv0, ain0);
            ahr0 = dot4h(wrh, hv0, ahr0);
            ahz0 = dot4h(wzh, hv0, ahz0);
            ahn0 = dot4h(wnh, hv0, ahn0);
            air1 = dot4h(wri, zv1, air1);
            aiz1 = dot4h(wzi, zv1, aiz1);
            ain1 = dot4h(wni, zv1, ain1);
            ahr1 = dot4h(wrh, hv1, ahr1);
            ahz1 = dot4h(wzh, hv1, ahz1);
            ahn1 = dot4h(wnh, hv1, ahn1);
        }
        {
            float r = fsig(air0 + ahr0);
            float z = fsig(aiz0 + ahz0);
            float g = ftanh(ain0 + r * ahn0);
            hr0 = (1.f - z) * g + z * hr0;
            hls[(nb + 0) * 32 + c] = __float2half_rn(hr0);
        }
        {
            float r = fsig(air1 + ahr1);
            float z = fsig(aiz1 + ahz1);
            float g = ftanh(ain1 + r * ahn1);
            hr1 = (1.f - z) * g + z * hr1;
            hls[(nb + 1) * 32 + c] = __float2half_rn(hr1);
        }
        __syncthreads();
    }

    float wo = sWout[c];
    float s0 = lane32_sum(hr0 * wo);
    float s1 = lane32_sum(hr1 * wo);
    if (c == 0) {
        float bo = bout[0];
        out[gbase + nb + 0] = s0 + bo;
        out[gbase + nb + 1] = s1 + bo;
    }
}

extern "C" void kernel_launch(void* const* d_in, const int* in_sizes, int n_in,
                              void* d_out, int out_size, void* d_ws, size_t ws_size,
                              hipStream_t stream) {
    const float* x      = (const float*)d_in[0];   // T*N
    const int* eidx     = (const int*)d_in[1];     // T*2*E
    const float* W1     = (const float*)d_in[2];
    const float* a_src1 = (const float*)d_in[3];
    const float* a_dst1 = (const float*)d_in[4];
    const float* b1     = (const float*)d_in[5];
    const float* W2     = (const float*)d_in[6];
    const float* a_src2 = (const float*)d_in[7];
    const float* a_dst2 = (const float*)d_in[8];
    const float* b2     = (const float*)d_in[9];
    const float* W_ih   = (const float*)d_in[10];
    const float* W_hh   = (const float*)d_in[11];
    const float* b_ih   = (const float*)d_in[12];
    const float* b_hh   = (const float*)d_in[13];
    const float* W_out  = (const float*)d_in[14];
    const float* b_out  = (const float*)d_in[15];
    float* out = (float*)d_out;

    char* base_ws = (char*)d_ws;
    size_t off = 0;
    auto alloc = [&](size_t bytes) {
        char* p = base_ws + off;
        off = (off + bytes + 15) & ~(size_t)15;
        return p;
    };
    int* cnt             = (int*)alloc((size_t)TN * 4);
    int* row             = (int*)alloc((size_t)(TN + 1) * 4);
    int* bsum            = (int*)alloc((size_t)SCAN_BLOCKS * 4);
    int* bpre            = (int*)alloc((size_t)SCAN_BLOCKS * 4);
    float* inv           = (float*)alloc((size_t)TN * 2 * 4);
    __half* h2h          = (__half*)alloc((size_t)TN * HDIM * 2);   // 10.24 MB
    __half* sh           = (__half*)alloc((size_t)TN * 2);          // 320 KB
    float* ad2           = (float*)alloc((size_t)TN * 4);
    __half* z2h          = (__half*)alloc((size_t)TN * HDIM * 2);   // 10.24 MB
    float* S4            = (float*)alloc(16);
    unsigned short* es   = (unsigned short*)alloc((size_t)TE * 2);  // 10.24 MB
    int* bbase           = (int*)alloc((size_t)T_STEPS * GB * NPAIR * 4);   // 10.24 MB
    unsigned short* stagedG = (unsigned short*)alloc((size_t)TE * 2);       // 10.24 MB
    // Aliases (stream-order safe):
    //  h2h region = hist8 (5.12 MB u8) + lrow16 (5.12 MB u16): written by
    //  hist, read by blkpre/scatter; h2h written later by node1.
    unsigned char* hist8   = (unsigned char*)h2h;
    unsigned short* lrow16 = (unsigned short*)((char*)h2h + (size_t)T_STEPS * GB * N_NODES);

    const int B = 256;
    k_hist<<<8 * GB, 1024, 0, stream>>>(eidx, hist8, lrow16, stagedG);
    k_blkpre<<<(T_STEPS * NPAIR + B - 1) / B, B, 0, stream>>>(hist8, bbase, cnt,
                                                              W1, a_src1, a_dst1, S4);
    k_scan_a<<<SCAN_BLOCKS, B, 0, stream>>>(cnt, bsum);
    k_scan_b<<<1, B, 0, stream>>>(bsum, bpre);
    k_scan_c<<<SCAN_BLOCKS, B, 0, stream>>>(cnt, bpre, row);
    k_scatter<<<8 * GB, 512, 0, stream>>>(hist8, lrow16, row, bbase, stagedG, es);

    k_gat1red<<<TN / 256, B, 0, stream>>>(es, row, x, S4, inv);
    k_node1<<<TN / NPB, B, 0, stream>>>(inv, W1, b1, W2, a_src2, a_dst2, h2h, sh, ad2);
    k_gat2red<<<8 * G2BLK, B, 0, stream>>>(es, row, sh, ad2, h2h, b2, z2h);

    k_gru_all<<<N_NODES / GNB, B, 0, stream>>>(z2h, W_ih, W_hh, b_ih, b_hh, W_out, b_out, out);
}

// Round 27
// 244.610 us; speedup vs baseline: 1.1174x; 1.1000x over previous
//
#include <hip/hip_runtime.h>
#include <hip/hip_fp16.h>
#include <math.h>

#define N_NODES 20000
#define T_STEPS 8
#define E_EDGES 640000
#define TN (T_STEPS * N_NODES)   // 160000
#define TE (T_STEPS * E_EDGES)   // 5120000
#define HDIM 32
#define HEADS 2
#define NPB 8                    // nodes per block for lane-parallel node kernels
#define SCAN_BLOCKS 625          // TN / 256 exactly
#define GB 32                    // histogram blocks per timestep
#define CHUNK (E_EDGES / GB)     // 20000 edges per histogram block
#define NPAIR (N_NODES / 2)      // packed bins per timestep
#define GNT 2                    // GRU nodes per thread-group
#define GNB (8 * GNT)            // GRU nodes per block = 16 (1250 blocks exactly)
#define G2NB 64                  // gat2red nodes per block (256 thr, 4 lanes/node)
#define G2BLK ((N_NODES + G2NB - 1) / G2NB)  // 313 blocks per timestep
#define SSPLIT 4                 // scatter range split (occupancy lever)
#define SPART (NPAIR / SSPLIT)   // 2500 bin-pairs per scatter block

typedef _Float16 h2v __attribute__((ext_vector_type(2)));

__device__ __forceinline__ float lrelu02(float v) { return fmaxf(v, 0.2f * v); }
__device__ __forceinline__ float eluf(float v) { return v > 0.f ? v : expm1f(v); }
__device__ __forceinline__ float fsig(float v) {
    return __fdividef(1.f, 1.f + __expf(-v));
}
__device__ __forceinline__ float ftanh(float v) {
    return 1.f - __fdividef(2.f, __expf(2.f * v) + 1.f);
}

__device__ __forceinline__ float lane32_sum(float v) {
    v += __shfl_xor(v, 16);
    v += __shfl_xor(v, 8);
    v += __shfl_xor(v, 4);
    v += __shfl_xor(v, 2);
    v += __shfl_xor(v, 1);
    return v;
}

// dot of 4 halves x 4 halves accumulated into f32 (2x v_dot2_f32_f16)
__device__ __forceinline__ float dot4h(uint2 a, uint2 b, float c) {
    h2v a0 = *(h2v*)&a.x, a1 = *(h2v*)&a.y;
    h2v b0 = *(h2v*)&b.x, b1 = *(h2v*)&b.y;
    return __builtin_amdgcn_fdot2(a0, b0, __builtin_amdgcn_fdot2(a1, b1, c, false), false);
}

// load 8 fp16 channels (16 B, one dwordx4) -> two float4
__device__ __forceinline__ void ldh8(const __half* p, float4& f0, float4& f1) {
    uint4 u = *(const uint4*)p;
    __half2 a = *(__half2*)&u.x;
    __half2 b = *(__half2*)&u.y;
    __half2 c = *(__half2*)&u.z;
    __half2 d = *(__half2*)&u.w;
    float2 fa = __half22float2(a), fb = __half22float2(b);
    float2 fc = __half22float2(c), fd = __half22float2(d);
    f0 = make_float4(fa.x, fa.y, fb.x, fb.y);
    f1 = make_float4(fc.x, fc.y, fd.x, fd.y);
}

// ---- pass A: per-block LDS histogram + local scan + locally-sorted staging ----
__global__ void k_hist(const int* __restrict__ ei, unsigned char* __restrict__ hist8,
                       unsigned short* __restrict__ lrow16,
                       unsigned short* __restrict__ stagedG) {
    __shared__ int lh[NPAIR];                 // 40 KB: counts -> packed lrow
    __shared__ unsigned short sdst[CHUNK];    // 40 KB
    __shared__ unsigned short ssrc[CHUNK];    // 40 KB
    __shared__ int partial[1024];             // 4 KB
    int t = blockIdx.x & 7, b = blockIdx.x >> 3;
    for (int i = threadIdx.x; i < NPAIR; i += 1024) lh[i] = 0;
    __syncthreads();
    const int* srcp = ei + (size_t)t * 2 * E_EDGES + b * CHUNK;
    const int* dstp = srcp + E_EDGES;
    for (int j = threadIdx.x; j < CHUNK; j += 1024) {
        int dst = dstp[j];
        int src = srcp[j];
        sdst[j] = (unsigned short)dst;
        ssrc[j] = (unsigned short)src;
        atomicAdd(&lh[dst >> 1], (dst & 1) ? 65536 : 1);
    }
    __syncthreads();
    size_t bi = (size_t)t * GB + b;
    unsigned char* hp = hist8 + bi * N_NODES;
    for (int i = threadIdx.x; i < NPAIR; i += 1024) {
        int v = lh[i];
        uchar2 pk;
        pk.x = (unsigned char)(v & 0xff);
        pk.y = (unsigned char)((v >> 16) & 0xff);
        *(uchar2*)(hp + 2 * i) = pk;
    }
    __syncthreads();
    const int tpp = 10;   // 1024*10 >= NPAIR
    int i0 = threadIdx.x * tpp;
    int run = 0;
    for (int k = 0; k < tpp; ++k) {
        int i = i0 + k;
        if (i < NPAIR) {
            int v = lh[i];
            run += (v & 0xffff) + (v >> 16);
        }
    }
    partial[threadIdx.x] = run;
    __syncthreads();
    for (int off = 1; off < 1024; off <<= 1) {
        int add = (threadIdx.x >= off) ? partial[threadIdx.x - off] : 0;
        __syncthreads();
        partial[threadIdx.x] += add;
        __syncthreads();
    }
    int run2 = (threadIdx.x > 0) ? partial[threadIdx.x - 1] : 0;
    for (int k = 0; k < tpp; ++k) {
        int i = i0 + k;
        if (i < NPAIR) {
            int v = lh[i];
            int c0 = v & 0xffff, c1 = v >> 16;
            lh[i] = run2 | ((run2 + c0) << 16);   // packed (l0, l1)
            run2 += c0 + c1;
        }
    }
    __syncthreads();
    unsigned short* lp = lrow16 + bi * NPAIR;
    for (int i = threadIdx.x; i < NPAIR; i += 1024)
        lp[i] = (unsigned short)(lh[i] & 0xffff);
    __syncthreads();   // all lrow reads of lh done before atomics mutate lh
    unsigned short* stg = stagedG + bi * CHUNK;
    for (int j = threadIdx.x; j < CHUNK; j += 1024) {
        int dst = sdst[j];
        int old = atomicAdd(&lh[dst >> 1], (dst & 1) ? 65536 : 1);
        int pos = (old >> (16 * (dst & 1))) & 0xffff;
        stg[pos] = ssrc[j];
    }
}

// ---- pass B: per-(t,dst) prefix over blocks -> base (packed) + totals ----
__global__ void k_blkpre(const unsigned char* __restrict__ hist8, int* __restrict__ base,
                         int* __restrict__ cnt, const float* __restrict__ W1,
                         const float* __restrict__ as1, const float* __restrict__ ad1,
                         float* __restrict__ S4) {
    int i = blockIdx.x * blockDim.x + threadIdx.x;  // (t, pair)
    if (i == 0) {
        for (int hd = 0; hd < HEADS; ++hd) {
            float ss = 0.f, sd = 0.f;
            for (int c = 0; c < HDIM; ++c) {
                ss += W1[hd * HDIM + c] * as1[hd * HDIM + c];
                sd += W1[hd * HDIM + c] * ad1[hd * HDIM + c];
            }
            S4[hd] = ss;
            S4[HEADS + hd] = sd;
        }
    }
    if (i >= T_STEPS * NPAIR) return;
    int t = i / NPAIR, pr = i % NPAIR;
    int a0 = 0, a1 = 0;
    for (int b = 0; b < GB; ++b) {
        size_t bi = ((size_t)t * GB + b);
        uchar2 v = *(const uchar2*)(hist8 + bi * N_NODES + 2 * pr);
        base[bi * NPAIR + pr] = a0 | (a1 << 16);
        a0 += v.x;
        a1 += v.y;
    }
    cnt[t * N_NODES + 2 * pr] = a0;
    cnt[t * N_NODES + 2 * pr + 1] = a1;
}

// ---- scan (exclusive) over cnt[TN] -> row[TN+1] ----
__global__ void k_scan_a(const int* __restrict__ cnt, int* __restrict__ bsum) {
    __shared__ int s[256];
    int i = blockIdx.x * 256 + threadIdx.x;
    s[threadIdx.x] = (i < TN) ? cnt[i] : 0;
    __syncthreads();
    for (int off = 128; off > 0; off >>= 1) {
        if (threadIdx.x < off) s[threadIdx.x] += s[threadIdx.x + off];
        __syncthreads();
    }
    if (threadIdx.x == 0) bsum[blockIdx.x] = s[0];
}

__global__ void k_scan_b(const int* __restrict__ bsum, int* __restrict__ bpre) {
    __shared__ int s[256];
    __shared__ int carry;
    if (threadIdx.x == 0) carry = 0;
    __syncthreads();
    for (int base = 0; base < SCAN_BLOCKS; base += 256) {
        int i = base + threadIdx.x;
        int v = (i < SCAN_BLOCKS) ? bsum[i] : 0;
        s[threadIdx.x] = v;
        __syncthreads();
        for (int off = 1; off < 256; off <<= 1) {
            int add = (threadIdx.x >= off) ? s[threadIdx.x - off] : 0;
            __syncthreads();
            s[threadIdx.x] += add;
            __syncthreads();
        }
        if (i < SCAN_BLOCKS) bpre[i] = carry + s[threadIdx.x] - v;  // exclusive
        __syncthreads();
        if (threadIdx.x == 0) carry += s[255];
        __syncthreads();
    }
}

__global__ void k_scan_c(const int* __restrict__ cnt, const int* __restrict__ bpre,
                         int* __restrict__ row) {
    __shared__ int s[256];
    int i = blockIdx.x * 256 + threadIdx.x;
    int v = (i < TN) ? cnt[i] : 0;
    s[threadIdx.x] = v;
    __syncthreads();
    for (int off = 1; off < 256; off <<= 1) {
        int add = (threadIdx.x >= off) ? s[threadIdx.x - off] : 0;
        __syncthreads();
        s[threadIdx.x] += add;
        __syncthreads();
    }
    if (i < TN) row[i] = bpre[blockIdx.x] + s[threadIdx.x] - v;
    if (blockIdx.x == 0 && threadIdx.x == 0) row[TN] = TE;
}

// ---- pass C: per-bin copy from locally-sorted staging into global CSR.
// Round-26: 4-way range split (grid 1024 blocks) — was latency-bound at
// 17.7% occupancy with 256 blocks.
__global__ void k_scatter(const unsigned char* __restrict__ hist8,
                          const unsigned short* __restrict__ lrow16,
                          const int* __restrict__ row, const int* __restrict__ base,
                          const unsigned short* __restrict__ stagedG,
                          unsigned short* __restrict__ es) {
    int bid = blockIdx.x;
    int t = bid & 7;
    int b = (bid >> 3) & 31;          // 0..31
    int part = bid >> 8;              // 0..SSPLIT-1
    size_t bi = (size_t)t * GB + b;
    const unsigned char* h8 = hist8 + bi * N_NODES;
    const unsigned short* lr = lrow16 + bi * NPAIR;
    const int* bs = base + bi * NPAIR;
    const unsigned short* stg = stagedG + bi * CHUNK;
    const int* rw = row + t * N_NODES;
    int i0 = part * SPART, i1 = i0 + SPART;
    for (int i = i0 + threadIdx.x; i < i1; i += blockDim.x) {
        uchar2 c = *(const uchar2*)(h8 + 2 * i);
        int l0 = lr[i];
        int l1 = l0 + c.x;
        int bp = bs[i];
        int b0 = bp & 0xffff, b1 = (bp >> 16) & 0xffff;
        int2 rr = *(const int2*)(rw + 2 * i);
        for (int k = 0; k < c.x; ++k) es[rr.x + b0 + k] = stg[l0 + k];
        for (int k = 0; k < c.y; ++k) es[rr.y + b1 + k] = stg[l1 + k];
    }
}

// ---- GAT1 reduce: ONE THREAD per (t,dst) bin; ushort4 es loads + unroll-4 ----
__global__ void k_gat1red(const unsigned short* __restrict__ es, const int* __restrict__ row,
                          const float* __restrict__ x, const float* __restrict__ S4,
                          float* __restrict__ inv) {
    int wid = blockIdx.x * 256 + threadIdx.x;  // grid exact: 625*256 == TN
    int t = wid / N_NODES;
    int start = row[wid], end = row[wid + 1];
    float Ss0 = S4[0], Ss1 = S4[1], Sd0 = S4[2], Sd1 = S4[3];
    float xd = x[wid];
    float a0 = xd * Sd0, a1 = xd * Sd1;
    const float* xt = x + (size_t)t * N_NODES;
    // self-loop init
    float w0 = __expf(lrelu02(fmaf(xd, Ss0, a0))), w1 = __expf(lrelu02(fmaf(xd, Ss1, a1)));
    float d0 = w0, n0 = w0 * xd, d1 = w1, n1 = w1 * xd;

#define G1E(xs) { \
    float v0 = __expf(lrelu02(fmaf(xs, Ss0, a0))); \
    float v1 = __expf(lrelu02(fmaf(xs, Ss1, a1))); \
    d0 += v0; n0 = fmaf(v0, xs, n0); \
    d1 += v1; n1 = fmaf(v1, xs, n1); }

    int p = start;
    {
        int nh = (4 - (start & 3)) & 3;
        if (nh > end - start) nh = end - start;
        if (nh > 0) {
            float xa = xt[es[p]];
            float xb = (nh > 1) ? xt[es[p + 1]] : 0.f;
            float xc = (nh > 2) ? xt[es[p + 2]] : 0.f;
            G1E(xa)
            if (nh > 1) G1E(xb)
            if (nh > 2) G1E(xc)
            p += nh;
        }
    }
    for (; p + 3 < end; p += 4) {
        ushort4 e4 = *(const ushort4*)(es + p);
        float xa = xt[e4.x], xb = xt[e4.y], xc = xt[e4.z], xe = xt[e4.w];
        float va0 = __expf(lrelu02(fmaf(xa, Ss0, a0)));
        float va1 = __expf(lrelu02(fmaf(xa, Ss1, a1)));
        float vb0 = __expf(lrelu02(fmaf(xb, Ss0, a0)));
        float vb1 = __expf(lrelu02(fmaf(xb, Ss1, a1)));
        float vc0 = __expf(lrelu02(fmaf(xc, Ss0, a0)));
        float vc1 = __expf(lrelu02(fmaf(xc, Ss1, a1)));
        float ve0 = __expf(lrelu02(fmaf(xe, Ss0, a0)));
        float ve1 = __expf(lrelu02(fmaf(xe, Ss1, a1)));
        d0 += va0 + vb0 + vc0 + ve0;
        d1 += va1 + vb1 + vc1 + ve1;
        n0 = fmaf(va0, xa, fmaf(vb0, xb, fmaf(vc0, xc, fmaf(ve0, xe, n0))));
        n1 = fmaf(va1, xa, fmaf(vb1, xb, fmaf(vc1, xc, fmaf(ve1, xe, n1))));
    }
    {
        int nt = end - p;
        if (nt > 0) {
            float xa = xt[es[p]];
            float xb = (nt > 1) ? xt[es[p + 1]] : 0.f;
            float xc = (nt > 2) ? xt[es[p + 2]] : 0.f;
            G1E(xa)
            if (nt > 1) G1E(xb)
            if (nt > 2) G1E(xc)
        }
    }
#undef G1E
    inv[(size_t)wid * 2 + 0] = n0 / (d0 + 1e-16f);
    inv[(size_t)wid * 2 + 1] = n1 / (d1 + 1e-16f);
}

// ---- GAT1 epilogue + h2 = elu(z1) @ W2, FP16 dot2 matvec ----
__global__ void k_node1(const float* __restrict__ inv, const float* __restrict__ W1,
                        const float* __restrict__ b1, const float* __restrict__ W2,
                        const float* __restrict__ as2w, const float* __restrict__ ad2w,
                        __half* __restrict__ h2h, __half* __restrict__ sh,
                        float* __restrict__ ad2) {
    __shared__ float sW1[HEADS * HDIM];
    __shared__ float sb1[HEADS * HDIM];
    __shared__ __half sW2T[HDIM * 64];        // [c][k], swizzled chunks
    __shared__ float sas[HDIM], sad[HDIM];
    __shared__ __half z1h[NPB][HEADS * HDIM]; // [8][64] fp16

    for (int i = threadIdx.x; i < HEADS * HDIM; i += blockDim.x) {
        sW1[i] = W1[i];
        sb1[i] = b1[i];
    }
    for (int i = threadIdx.x; i < HEADS * HDIM * HDIM; i += blockDim.x) {
        int k = i >> 5, c = i & 31;
        int j = k >> 2;                       // true chunk
        int js = j ^ (c & 15);                // stored chunk slot
        sW2T[c * 64 + (js << 2) + (k & 3)] = __float2half_rn(W2[i]);
    }
    for (int i = threadIdx.x; i < HDIM; i += blockDim.x) {
        sas[i] = as2w[i];
        sad[i] = ad2w[i];
    }
    __syncthreads();

    int ln = threadIdx.x >> 5;
    int c = threadIdx.x & 31;
    int tn = blockIdx.x * NPB + ln;
    if (tn >= TN) return;

    float inv0 = inv[(size_t)tn * 2 + 0];
    float inv1 = inv[(size_t)tn * 2 + 1];
    z1h[ln][c] = __float2half_rn(eluf(inv0 * sW1[c] + sb1[c]));
    z1h[ln][HDIM + c] = __float2half_rn(eluf(inv1 * sW1[HDIM + c] + sb1[HDIM + c]));
    __syncthreads();

    float acc = 0.f;
    const int key = c & 15;
#pragma unroll
    for (int j = 0; j < 16; ++j) {
        uint2 w = *(const uint2*)&sW2T[c * 64 + ((j ^ key) << 2)];
        uint2 z = *(const uint2*)&z1h[ln][j << 2];
        acc = dot4h(w, z, acc);
    }

    h2h[(size_t)tn * HDIM + c] = __float2half_rn(acc);
    float s = lane32_sum(acc * sas[c]);
    float d = lane32_sum(acc * sad[c]);
    if (c == 0) {
        sh[tn] = __float2half_rn(s);   // src logit (fp16)
        ad2[tn] = d;
    }
}

// ---- GAT2 reduce: 256 threads = 64 nodes x 4 lanes x 8 channels;
// full timestep logit table staged in LDS (40 KB) ----
__global__ void k_gat2red(const unsigned short* __restrict__ es, const int* __restrict__ row,
                          const __half* __restrict__ sh, const float* __restrict__ ad2,
                          const __half* __restrict__ h2h, const float* __restrict__ b2,
                          __half* __restrict__ z2h) {
    __shared__ __half shl[N_NODES];   // 40 KB: full logit table for timestep t
    int b = blockIdx.x;
    int t = b & 7;             // XCD pin
    int chunk = b >> 3;        // 0..312
    const __half* sht = sh + (size_t)t * N_NODES;
    // stage logits (coalesced uint4: 2500 x 16B)
    for (int i = threadIdx.x; i < N_NODES / 8; i += 256)
        *(uint4*)&shl[i * 8] = *(const uint4*)&sht[i * 8];
    __syncthreads();

    int u = threadIdx.x >> 2;  // node slot 0..63
    int l = threadIdx.x & 3;   // channel octet: channels 8l..8l+7
    int node = chunk * G2NB + u;
    if (node >= N_NODES) return;
    int wid = t * N_NODES + node;

    int start = row[wid], end = row[wid + 1];
    float ad = ad2[wid];
    const __half* h2t = h2h + (size_t)t * N_NODES * HDIM;

    float4 a0 = make_float4(0.f, 0.f, 0.f, 0.f);
    float4 a1 = make_float4(0.f, 0.f, 0.f, 0.f);
    float den = 0.f;

#define G2E(sv) { \
    float w = __expf(lrelu02(__half2float(shl[sv]) + ad)); \
    float4 ha, hb; \
    ldh8(h2t + (size_t)(sv) * HDIM + 8 * l, ha, hb); \
    a0.x = fmaf(w, ha.x, a0.x); a0.y = fmaf(w, ha.y, a0.y); \
    a0.z = fmaf(w, ha.z, a0.z); a0.w = fmaf(w, ha.w, a0.w); \
    a1.x = fmaf(w, hb.x, a1.x); a1.y = fmaf(w, hb.y, a1.y); \
    a1.z = fmaf(w, hb.z, a1.z); a1.w = fmaf(w, hb.w, a1.w); \
    den += w; }

    int p = start;
    // head: align p to 4
    {
        int nh = (4 - (start & 3)) & 3;
        if (nh > end - start) nh = end - start;
        if (nh > 0) {
            int sh0 = es[p];
            int sh1 = (nh > 1) ? es[p + 1] : 0;
            int sh2 = (nh > 2) ? es[p + 2] : 0;
            G2E(sh0)
            if (nh > 1) G2E(sh1)
            if (nh > 2) G2E(sh2)
            p += nh;
        }
    }
    // main: 4 edges per iteration (one ushort4; 4 independent 16B gathers)
    for (; p + 3 < end; p += 4) {
        ushort4 eA = *(const ushort4*)(es + p);
        int s0 = eA.x, s1 = eA.y, s2 = eA.z, s3 = eA.w;
        float v0 = __half2float(shl[s0]), v1 = __half2float(shl[s1]);
        float v2 = __half2float(shl[s2]), v3 = __half2float(shl[s3]);
        float4 h0a, h0b, h1a, h1b, h2a, h2b, h3a, h3b;
        ldh8(h2t + (size_t)s0 * HDIM + 8 * l, h0a, h0b);
        ldh8(h2t + (size_t)s1 * HDIM + 8 * l, h1a, h1b);
        ldh8(h2t + (size_t)s2 * HDIM + 8 * l, h2a, h2b);
        ldh8(h2t + (size_t)s3 * HDIM + 8 * l, h3a, h3b);
        float w0 = __expf(lrelu02(v0 + ad));
        float w1 = __expf(lrelu02(v1 + ad));
        float w2 = __expf(lrelu02(v2 + ad));
        float w3 = __expf(lrelu02(v3 + ad));
        a0.x = fmaf(w0, h0a.x, fmaf(w1, h1a.x, fmaf(w2, h2a.x, fmaf(w3, h3a.x, a0.x))));
        a0.y = fmaf(w0, h0a.y, fmaf(w1, h1a.y, fmaf(w2, h2a.y, fmaf(w3, h3a.y, a0.y))));
        a0.z = fmaf(w0, h0a.z, fmaf(w1, h1a.z, fmaf(w2, h2a.z, fmaf(w3, h3a.z, a0.z))));
        a0.w = fmaf(w0, h0a.w, fmaf(w1, h1a.w, fmaf(w2, h2a.w, fmaf(w3, h3a.w, a0.w))));
        a1.x = fmaf(w0, h0b.x, fmaf(w1, h1b.x, fmaf(w2, h2b.x, fmaf(w3, h3b.x, a1.x))));
        a1.y = fmaf(w0, h0b.y, fmaf(w1, h1b.y, fmaf(w2, h2b.y, fmaf(w3, h3b.y, a1.y))));
        a1.z = fmaf(w0, h0b.z, fmaf(w1, h1b.z, fmaf(w2, h2b.z, fmaf(w3, h3b.z, a1.z))));
        a1.w = fmaf(w0, h0b.w, fmaf(w1, h1b.w, fmaf(w2, h2b.w, fmaf(w3, h3b.w, a1.w))));
        den += w0 + w1 + w2 + w3;
    }
    // tail: <=3 scalar
    {
        int nt = end - p;
        if (nt > 0) {
            int st0 = es[p];
            int st1 = (nt > 1) ? es[p + 1] : 0;
            int st2 = (nt > 2) ? es[p + 2] : 0;
            G2E(st0)
            if (nt > 1) G2E(st1)
            if (nt > 2) G2E(st2)
        }
    }
    // self-loop
    G2E(node)
#undef G2E

    float invd = 1.f / (den + 1e-16f);
    float4 bb0 = *(const float4*)(b2 + 8 * l);
    float4 bb1 = *(const float4*)(b2 + 8 * l + 4);
    __half o0 = __float2half_rn(eluf(fmaf(a0.x, invd, bb0.x)));
    __half o1 = __float2half_rn(eluf(fmaf(a0.y, invd, bb0.y)));
    __half o2 = __float2half_rn(eluf(fmaf(a0.z, invd, bb0.z)));
    __half o3 = __float2half_rn(eluf(fmaf(a0.w, invd, bb0.w)));
    __half o4 = __float2half_rn(eluf(fmaf(a1.x, invd, bb1.x)));
    __half o5 = __float2half_rn(eluf(fmaf(a1.y, invd, bb1.y)));
    __half o6 = __float2half_rn(eluf(fmaf(a1.z, invd, bb1.z)));
    __half o7 = __float2half_rn(eluf(fmaf(a1.w, invd, bb1.w)));
    ushort4 pk0, pk1;
    pk0.x = *(unsigned short*)&o0; pk0.y = *(unsigned short*)&o1;
    pk0.z = *(unsigned short*)&o2; pk0.w = *(unsigned short*)&o3;
    pk1.x = *(unsigned short*)&o4; pk1.y = *(unsigned short*)&o5;
    pk1.z = *(unsigned short*)&o6; pk1.w = *(unsigned short*)&o7;
    *(ushort4*)(z2h + (size_t)wid * HDIM + 8 * l) = pk0;
    *(ushort4*)(z2h + (size_t)wid * HDIM + 8 * l + 4) = pk1;
}

// ---- fused 8-step GRU + output projection, FP16 weights + v_dot2_f32_f16 ----
__global__ void k_gru_all(const __half* __restrict__ z2h, const float* __restrict__ Wih,
                          const float* __restrict__ Whh, const float* __restrict__ bih,
                          const float* __restrict__ bhh, const float* __restrict__ Wout,
                          const float* __restrict__ bout, float* __restrict__ out) {
    __shared__ __half sWih[3 * HDIM * 32];  // 6 KB, swizzled
    __shared__ __half sWhh[3 * HDIM * 32];
    __shared__ float sbih[3 * HDIM], sbhh[3 * HDIM], sWout[HDIM];
    __shared__ __half hls[GNB * 32];        // 1 KB
    __shared__ __half zls[GNB * 32];

    for (int i = threadIdx.x; i < 3 * HDIM * HDIM; i += 256) {
        int r = i >> 5, cc = i & 31;
        int key = (r ^ (r >> 3)) & 7;
        int pos = r * 32 + ((((cc >> 2) ^ key) << 2) | (cc & 3));
        sWih[pos] = __float2half_rn(Wih[i]);
        sWhh[pos] = __float2half_rn(Whh[i]);
    }
    for (int i = threadIdx.x; i < 3 * HDIM; i += 256) {
        sbih[i] = bih[i];
        sbhh[i] = bhh[i];
    }
    for (int i = threadIdx.x; i < HDIM; i += 256) sWout[i] = Wout[i];
    for (int i = threadIdx.x; i < GNB * 32; i += 256) hls[i] = __float2half_rn(0.f);
    __syncthreads();

    const int c = threadIdx.x & 31;
    const int nb = (threadIdx.x >> 5) * GNT;
    const int gbase = blockIdx.x * GNB;
    const int rR = c, rZ = HDIM + c, rN = 2 * HDIM + c;
    const int kR = (rR ^ (rR >> 3)) & 7;
    const int kZ = (rZ ^ (rZ >> 3)) & 7;
    const int kN = (rN ^ (rN >> 3)) & 7;

    const float br = sbih[c], bz = sbih[HDIM + c], bn = sbih[2 * HDIM + c];
    const float cr = sbhh[c], cz = sbhh[HDIM + c], cn = sbhh[2 * HDIM + c];

    float air0, aiz0, ain0, ahr0, ahz0, ahn0, hr0;
    float air1, aiz1, ain1, ahr1, ahz1, ahn1, hr1;
    hr0 = hr1 = 0.f;

    for (int t = 0; t < T_STEPS; ++t) {
        const uint2* zsrc = (const uint2*)(z2h + ((size_t)t * N_NODES + gbase) * HDIM);
        if (threadIdx.x < GNB * 8)
            *(uint2*)&zls[threadIdx.x * 4] = zsrc[threadIdx.x];
        __syncthreads();

        air0 = air1 = br;
        aiz0 = aiz1 = bz;
        ain0 = ain1 = bn;
        ahr0 = ahr1 = cr;
        ahz0 = ahz1 = cz;
        ahn0 = ahn1 = cn;
#pragma unroll 2
        for (int q = 0; q < 8; ++q) {
            int kq = q << 2;
            uint2 wri = *(const uint2*)&sWih[rR * 32 + ((q ^ kR) << 2)];
            uint2 wzi = *(const uint2*)&sWih[rZ * 32 + ((q ^ kZ) << 2)];
            uint2 wni = *(const uint2*)&sWih[rN * 32 + ((q ^ kN) << 2)];
            uint2 wrh = *(const uint2*)&sWhh[rR * 32 + ((q ^ kR) << 2)];
            uint2 wzh = *(const uint2*)&sWhh[rZ * 32 + ((q ^ kZ) << 2)];
            uint2 wnh = *(const uint2*)&sWhh[rN * 32 + ((q ^ kN) << 2)];
            uint2 zv0 = *(const uint2*)&zls[(nb + 0) * 32 + kq];
            uint2 hv0 = *(const uint2*)&hls[(nb + 0) * 32 + kq];
            uint2 zv1 = *(const uint2*)&zls[(nb + 1) * 32 + kq];
            uint2 hv1 = *(const uint2*)&hls[(nb + 1) * 32 + kq];
            air0 = dot4h(wri, zv0, air0);
            aiz0 = dot4h(wzi, zv0, aiz0);
            ain0 = dot4h(wni, zv0, ain0);
            ahr0 = dot4h(wrh, hv0, ahr0);
            ahz0 = dot4h(wzh, hv0, ahz0);
            ahn0 = dot4h(wnh, hv0, ahn0);
            air1 = dot4h(wri, zv1, air1);
            aiz1 = dot4h(wzi, zv1, aiz1);
            ain1 = dot4h(wni, zv1, ain1);
            ahr1 = dot4h(wrh, hv1, ahr1);
            ahz1 = dot4h(wzh, hv1, ahz1);
            ahn1 = dot4h(wnh, hv1, ahn1);
        }
        {
            float r = fsig(air0 + ahr0);
            float z = fsig(aiz0 + ahz0);
            float g = ftanh(ain0 + r * ahn0);
            hr0 = (1.f - z) * g + z * hr0;
            hls[(nb + 0) * 32 + c] = __float2half_rn(hr0);
        }
        {
            float r = fsig(air1 + ahr1);
            float z = fsig(aiz1 + ahz1);
            float g = ftanh(ain1 + r * ahn1);
            hr1 = (1.f - z) * g + z * hr1;
            hls[(nb + 1) * 32 + c] = __float2half_rn(hr1);
        }
        __syncthreads();
    }

    float wo = sWout[c];
    float s0 = lane32_sum(hr0 * wo);
    float s1 = lane32_sum(hr1 * wo);
    if (c == 0) {
        float bo = bout[0];
        out[gbase + nb + 0] = s0 + bo;
        out[gbase + nb + 1] = s1 + bo;
    }
}

extern "C" void kernel_launch(void* const* d_in, const int* in_sizes, int n_in,
                              void* d_out, int out_size, void* d_ws, size_t ws_size,
                              hipStream_t stream) {
    const float* x      = (const float*)d_in[0];   // T*N
    const int* eidx     = (const int*)d_in[1];     // T*2*E
    const float* W1     = (const float*)d_in[2];
    const float* a_src1 = (const float*)d_in[3];
    const float* a_dst1 = (const float*)d_in[4];
    const float* b1     = (const float*)d_in[5];
    const float* W2     = (const float*)d_in[6];
    const float* a_src2 = (const float*)d_in[7];
    const float* a_dst2 = (const float*)d_in[8];
    const float* b2     = (const float*)d_in[9];
    const float* W_ih   = (const float*)d_in[10];
    const float* W_hh   = (const float*)d_in[11];
    const float* b_ih   = (const float*)d_in[12];
    const float* b_hh   = (const float*)d_in[13];
    const float* W_out  = (const float*)d_in[14];
    const float* b_out  = (const float*)d_in[15];
    float* out = (float*)d_out;

    char* base_ws = (char*)d_ws;
    size_t off = 0;
    auto alloc = [&](size_t bytes) {
        char* p = base_ws + off;
        off = (off + bytes + 15) & ~(size_t)15;
        return p;
    };
    int* cnt             = (int*)alloc((size_t)TN * 4);
    int* row             = (int*)alloc((size_t)(TN + 1) * 4);
    int* bsum            = (int*)alloc((size_t)SCAN_BLOCKS * 4);
    int* bpre            = (int*)alloc((size_t)SCAN_BLOCKS * 4);
    float* inv           = (float*)alloc((size_t)TN * 2 * 4);
    __half* h2h          = (__half*)alloc((size_t)TN * HDIM * 2);   // 10.24 MB
    __half* sh           = (__half*)alloc((size_t)TN * 2);          // 320 KB
    float* ad2           = (float*)alloc((size_t)TN * 4);
    __half* z2h          = (__half*)alloc((size_t)TN * HDIM * 2);   // 10.24 MB
    float* S4            = (float*)alloc(16);
    unsigned short* es   = (unsigned short*)alloc((size_t)TE * 2);  // 10.24 MB
    int* bbase           = (int*)alloc((size_t)T_STEPS * GB * NPAIR * 4);   // 10.24 MB
    unsigned short* stagedG = (unsigned short*)alloc((size_t)TE * 2);       // 10.24 MB
    // Aliases (stream-order safe):
    //  h2h region = hist8 (5.12 MB u8) + lrow16 (5.12 MB u16): written by
    //  hist, read by blkpre/scatter; h2h written later by node1.
    unsigned char* hist8   = (unsigned char*)h2h;
    unsigned short* lrow16 = (unsigned short*)((char*)h2h + (size_t)T_STEPS * GB * N_NODES);

    const int B = 256;
    k_hist<<<8 * GB, 1024, 0, stream>>>(eidx, hist8, lrow16, stagedG);
    k_blkpre<<<(T_STEPS * NPAIR + B - 1) / B, B, 0, stream>>>(hist8, bbase, cnt,
                                                              W1, a_src1, a_dst1, S4);
    k_scan_a<<<SCAN_BLOCKS, B, 0, stream>>>(cnt, bsum);
    k_scan_b<<<1, B, 0, stream>>>(bsum, bpre);
    k_scan_c<<<SCAN_BLOCKS, B, 0, stream>>>(cnt, bpre, row);
    k_scatter<<<8 * GB * SSPLIT, 512, 0, stream>>>(hist8, lrow16, row, bbase, stagedG, es);

    k_gat1red<<<TN / 256, B, 0, stream>>>(es, row, x, S4, inv);
    k_node1<<<TN / NPB, B, 0, stream>>>(inv, W1, b1, W2, a_src2, a_dst2, h2h, sh, ad2);
    k_gat2red<<<8 * G2BLK, B, 0, stream>>>(es, row, sh, ad2, h2h, b2, z2h);

    k_gru_all<<<N_NODES / GNB, B, 0, stream>>>(z2h, W_ih, W_hh, b_ih, b_hh, W_out, b_out, out);
}